// Round 11
// baseline (458.357 us; speedup 1.0000x reference)
//
#include <hip/hip_runtime.h>

#define B_ 1024
#define N_ 256
#define C_ 128
#define L_ 4

typedef __bf16 bf16x8 __attribute__((ext_vector_type(8)));
typedef float f32x4 __attribute__((ext_vector_type(4)));

__device__ __forceinline__ float b2f(unsigned short u) {
    union { unsigned int i; float f; } v; v.i = ((unsigned int)u) << 16; return v.f;
}
__device__ __forceinline__ unsigned short f2b(float f) {
    union { float f; unsigned int i; } v; v.f = f;
    unsigned int u = v.i;
    u = (u + 0x7FFFu + ((u >> 16) & 1u)) >> 16;
    return (unsigned short)u;
}

// ---------------------------------------------------------------------------
// Kernel 0: prep (bf16): wtp[br][0]=(W0-W2+I)^T, [1]=W1^T, [2]=(2W2)^T; adj bf16
// ---------------------------------------------------------------------------
extern "C" __global__ __launch_bounds__(256) void k_prep(
    const float* __restrict__ Wt,
    const float* __restrict__ Wf,
    const float* __restrict__ adjf,
    unsigned short* __restrict__ wtp,
    unsigned short* __restrict__ adj_bs)
{
    int i = blockIdx.x * 256 + threadIdx.x;      // [0, 163840)
    if (i < 98304) {
        int br = i / 49152;
        int r  = i - br * 49152;
        int mat = r >> 14;
        int r2  = r & 16383;
        int d = r2 >> 7, c = r2 & 127;
        const float* S = br ? Wf : Wt;
        float v;
        if (mat == 0) {
            v = S[c * 128 + d] - S[2 * 16384 + c * 128 + d] + (c == d ? 1.0f : 0.0f);
        } else if (mat == 1) {
            v = S[16384 + c * 128 + d];
        } else {
            v = 2.0f * S[2 * 16384 + c * 128 + d];
        }
        wtp[i] = f2b(v);
    } else {
        int j = i - 98304;                        // [0, 65536)
        adj_bs[j] = f2b(adjf[j]);
    }
}

// ---------------------------------------------------------------------------
// Kernel 0b: adj2 = bf16(adjf @ adjf). Block i = output row i; coalesced inner.
// ---------------------------------------------------------------------------
extern "C" __global__ __launch_bounds__(256) void k_adj2(
    const float* __restrict__ adjf,
    unsigned short* __restrict__ adj2_bs)
{
    __shared__ float rowi[256];
    const int i = blockIdx.x, j = threadIdx.x;
    rowi[j] = adjf[i * 256 + j];
    __syncthreads();
    float s = 0.f;
#pragma unroll 8
    for (int k = 0; k < 256; ++k) s += rowi[k] * adjf[k * 256 + j];
    adj2_bs[i * 256 + j] = f2b(s);
}

// ---------------------------------------------------------------------------
// Kernel 1: latent attention (+ x' production to ws). 512 threads.
// ---------------------------------------------------------------------------
extern "C" __global__ __launch_bounds__(512) void k_latent(
    const float* __restrict__ timep,
    const float* __restrict__ frep,
    const float* __restrict__ latents,
    const float* __restrict__ scale_tp,
    const float* __restrict__ scale_fp,
    float* __restrict__ fused_out,
    unsigned short* __restrict__ xpws,
    int do_xp)
{
    extern __shared__ char smem[];
    float* scr  = (float*)(smem + 131072);            // [4][512] scores
    float* part = (float*)(smem + 131072 + 8192);     // [4][2][128] partials
    float* lat  = (float*)(smem + 131072 + 12288);    // [4][128] latents -> fused
    const int t = threadIdx.x;
    const int b = blockIdx.x;
    const float4* tg = (const float4*)(timep + (size_t)b * (N_ * C_));
    const float4* fg = (const float4*)(frep  + (size_t)b * (N_ * C_));
#pragma unroll
    for (int i = 0; i < 32; ++i) {
        int ch = i * 512 + t;                     // [0,16384)
        const float4* p = (ch < 8192) ? (tg + ch) : (fg + (ch - 8192));
        float4 u = *p;
        int row = ch >> 5, c4 = ch & 31;
        unsigned short o[4] __attribute__((aligned(8)));
        o[0] = f2b(u.x); o[1] = f2b(u.y); o[2] = f2b(u.z); o[3] = f2b(u.w);
        *(uint2*)(smem + row * 256 + ((c4 * 8) ^ ((row & 7) << 4))) = *(const uint2*)o;
    }
    lat[t & 511] = latents[t & 511];
    __syncthreads();

    const float isc = 0.0883883476483184f;   // 1/sqrt(128)
    {   // scores vs latents: one row per thread
        const int jj = t;
        float s0 = 0, s1 = 0, s2 = 0, s3 = 0;
#pragma unroll
        for (int ci = 0; ci < 16; ++ci) {
            uint4 u = *(const uint4*)(smem + jj * 256 + ((ci * 16) ^ ((jj & 7) << 4)));
            const unsigned short* xb = (const unsigned short*)&u;
#pragma unroll
            for (int i = 0; i < 8; ++i) {
                float xv = b2f(xb[i]); int c = ci * 8 + i;
                s0 += xv * lat[c];           s1 += xv * lat[C_ + c];
                s2 += xv * lat[2 * C_ + c];  s3 += xv * lat[3 * C_ + c];
            }
        }
        scr[jj] = s0 * isc; scr[512 + jj] = s1 * isc;
        scr[1024 + jj] = s2 * isc; scr[1536 + jj] = s3 * isc;
    }
    __syncthreads();

    const int w = t >> 6, lane = t & 63;
    if (w < 4) {   // softmax over 512, wave w owns latent l=w
        float v[8]; float m = -1e30f;
#pragma unroll
        for (int i = 0; i < 8; ++i) { v[i] = scr[w * 512 + lane * 8 + i]; m = fmaxf(m, v[i]); }
#pragma unroll
        for (int off = 32; off >= 1; off >>= 1) m = fmaxf(m, __shfl_xor(m, off));
        float s = 0;
#pragma unroll
        for (int i = 0; i < 8; ++i) { v[i] = __expf(v[i] - m); s += v[i]; }
#pragma unroll
        for (int off = 32; off >= 1; off >>= 1) s += __shfl_xor(s, off);
        float inv = 1.0f / s;
#pragma unroll
        for (int i = 0; i < 8; ++i) scr[w * 512 + lane * 8 + i] = v[i] * inv;
    }
    __syncthreads();
    {   // weighted sum: wave w: latent l=w>>1, half jh=w&1; lane owns 2 channels
        const int l = w >> 1, jh = w & 1;
        float f0 = 0.f, f1 = 0.f;
        for (int j = jh * 256; j < jh * 256 + 256; ++j) {
            float p = scr[l * 512 + j];
            unsigned int pr = *(const unsigned int*)(smem + j * 256 + ((lane * 4) ^ ((j & 7) << 4)));
            f0 += p * b2f((unsigned short)(pr & 0xFFFFu));
            f1 += p * b2f((unsigned short)(pr >> 16));
        }
        part[(l * 2 + jh) * 128 + lane * 2]     = f0;
        part[(l * 2 + jh) * 128 + lane * 2 + 1] = f1;
    }
    __syncthreads();
    {
        int l = t >> 7, c = t & 127;
        float f = part[(l * 2) * 128 + c] + part[(l * 2 + 1) * 128 + c];
        lat[l * 128 + c] = f;
        fused_out[(size_t)b * 512 + l * 128 + c] = f;
    }
    __syncthreads();

    if (!do_xp) return;

    // ---- x' phase: thread owns row j
    {
        const int j = t;
        const int brx = j >> 8;
        const float scale = brx ? scale_fp[0] : scale_tp[0];
        float s0 = 0, s1 = 0, s2 = 0, s3 = 0;
#pragma unroll
        for (int ci = 0; ci < 16; ++ci) {
            uint4 u = *(const uint4*)(smem + j * 256 + ((ci * 16) ^ ((j & 7) << 4)));
            const unsigned short* xb = (const unsigned short*)&u;
#pragma unroll
            for (int i = 0; i < 8; ++i) {
                float xv = b2f(xb[i]); int c = ci * 8 + i;
                s0 += xv * lat[c];           s1 += xv * lat[C_ + c];
                s2 += xv * lat[2 * C_ + c];  s3 += xv * lat[3 * C_ + c];
            }
        }
        s0 *= isc; s1 *= isc; s2 *= isc; s3 *= isc;
        float m = fmaxf(fmaxf(s0, s1), fmaxf(s2, s3));
        float p0 = __expf(s0 - m), p1 = __expf(s1 - m), p2 = __expf(s2 - m), p3 = __expf(s3 - m);
        float inv = scale / (p0 + p1 + p2 + p3);
        p0 *= inv; p1 *= inv; p2 *= inv; p3 *= inv;
#pragma unroll
        for (int ci = 0; ci < 16; ++ci) {
            char* slot = smem + j * 256 + ((ci * 16) ^ ((j & 7) << 4));
            uint4 u = *(const uint4*)slot;
            const unsigned short* xb = (const unsigned short*)&u;
            unsigned short ov[8] __attribute__((aligned(16)));
#pragma unroll
            for (int i = 0; i < 8; ++i) {
                int c = ci * 8 + i;
                float v = b2f(xb[i]) + p0 * lat[c] + p1 * lat[C_ + c]
                        + p2 * lat[2 * C_ + c] + p3 * lat[3 * C_ + c];
                ov[i] = f2b(v);
            }
            *(uint4*)slot = *(const uint4*)ov;
        }
    }
    __syncthreads();

    // ---- coalesced copy-out: x'ws[(br*1024+b)*256 + n][c]
    {
#pragma unroll
        for (int i = 0; i < 16; ++i) {
            int ch = i * 512 + t;                 // 8192 chunks of 16B
            int row = ch >> 4, cj = ch & 15;
            uint4 u = *(const uint4*)(smem + row * 256 + ((cj * 16) ^ ((row & 7) << 4)));
            size_t off = (((size_t)(row >> 8) * B_ + b) * N_ + (row & 255)) * C_ + cj * 8;
            *(uint4*)(xpws + off) = u;
        }
    }
}

// ---------------------------------------------------------------------------
// Kernel 2 (fast v5, adj^2 form): block=(b,br), 8 waves.
//   out = x'W0'' + adj·(x'W1) + adj2·(x'·2W2) + b     -- NO serial Z chain.
// LDS 128KB: xs [256n][256B] swz @0 ; slC1 @64K, slC2 @96K: Y1T/Y2T chunks
//   ([128c][256B n-local] swz ^((c&7)<<4)).
// W0/W1/W2, adj, adj2 read from global (L2-broadcast). 4 barriers total.
// Phases: stage xs | G1a: accO=b+W0''T·xsT | per n-chunk: joint {Y1,Y2} ->
//   write both chunks -> accO += Y1T·adj + Y2T·adj2 (128-MFMA stretch).
// ---------------------------------------------------------------------------
extern "C" __global__ __launch_bounds__(512, 1) void k_cheb(
    const unsigned short* __restrict__ adj,       // bf16 [256][256], symmetric
    const unsigned short* __restrict__ adj2,      // bf16 [256][256], symmetric
    const unsigned short* __restrict__ wtp,
    const float* __restrict__ btp,
    const float* __restrict__ bfp,
    const unsigned short* __restrict__ xpws,
    float* __restrict__ outp)
{
    extern __shared__ char smem[];
    char* xs   = smem;            // 64KB
    char* slC1 = smem + 65536;    // 32KB
    char* slC2 = smem + 98304;    // 32KB
    const int t  = threadIdx.x;
    const int b  = blockIdx.x;
    const int br = blockIdx.y;
    const unsigned short* xw  = xpws + (((size_t)br * B_ + b) * N_) * C_;
    const unsigned short* wt0 = wtp + br * (3 * C_ * C_);
    const unsigned short* wt1 = wt0 + C_ * C_;
    const unsigned short* wt2 = wt0 + 2 * C_ * C_;
    const float* bias = br ? bfp : btp;
    float* og = outp + (size_t)br * B_ * N_ * C_ + (size_t)b * (N_ * C_);

    // ---- stage x' (4096 x 16B), swizzled
#pragma unroll
    for (int j = 0; j < 8; ++j) {
        int ch = j * 512 + t; int row = ch >> 4, ck = ch & 15;
        uint4 v = *(const uint4*)(xw + row * C_ + ck * 8);
        *(uint4*)(xs + row * 256 + ((ck * 16) ^ ((row & 7) << 4))) = v;
    }
    __syncthreads();

    const int w = t >> 6, lane = t & 63;
    const int lr = lane & 15, lq = lane >> 4;
    const int wct = w >> 2, wnt = w & 3;      // accO D[c][n]: 2 c-bands(64) x 4 n-bands(64)
    const int rn2 = w >> 2, cc4 = w & 3;      // joint-Y: 2 n-bands(64) x 4 c-bands(32)

    // ---- G1a: accO = bias + W0''T·xsT   (A wt0 global, B xs LDS), D[c][n]
    f32x4 accO[4][4];
#pragma unroll
    for (int fm = 0; fm < 4; ++fm) {
        float4 b4 = *(const float4*)(bias + wct * 64 + fm * 16 + lq * 4);
#pragma unroll
        for (int fn = 0; fn < 4; ++fn) accO[fm][fn] = f32x4{b4.x, b4.y, b4.z, b4.w};
    }
#pragma unroll
    for (int kk = 0; kk < 4; ++kk) {
        bf16x8 afr[4], bfr[4];
#pragma unroll
        for (int fm = 0; fm < 4; ++fm) {
            int d = wct * 64 + fm * 16 + lr;
            afr[fm] = __builtin_bit_cast(bf16x8, *(const uint4*)(wt0 + d * C_ + kk * 32 + lq * 8));
        }
#pragma unroll
        for (int fn = 0; fn < 4; ++fn) {
            int n = wnt * 64 + fn * 16 + lr;
            bfr[fn] = __builtin_bit_cast(bf16x8,
                *(const uint4*)(xs + n * 256 + ((kk * 64 + lq * 16) ^ ((n & 7) << 4))));
        }
#pragma unroll
        for (int fm = 0; fm < 4; ++fm)
#pragma unroll
            for (int fn = 0; fn < 4; ++fn)
                accO[fm][fn] = __builtin_amdgcn_mfma_f32_16x16x32_bf16(afr[fm], bfr[fn], accO[fm][fn], 0, 0, 0);
    }

    // ---- n-chunk loop (nk = 0,1; chunk = 128 rows of n)
    for (int nk = 0; nk < 2; ++nk) {
        // joint Y1,Y2 for this chunk: D[n][c], chunk [128n][128c]
        f32x4 a1[4][2], a2[4][2];
#pragma unroll
        for (int fm = 0; fm < 4; ++fm)
#pragma unroll
            for (int fn = 0; fn < 2; ++fn) {
                a1[fm][fn] = f32x4{0.f, 0.f, 0.f, 0.f};
                a2[fm][fn] = f32x4{0.f, 0.f, 0.f, 0.f};
            }
#pragma unroll
        for (int kk = 0; kk < 4; ++kk) {
            bf16x8 afr[4], b1[2], b2[2];
#pragma unroll
            for (int fm = 0; fm < 4; ++fm) {
                int n = nk * 128 + rn2 * 64 + fm * 16 + lr;
                afr[fm] = __builtin_bit_cast(bf16x8,
                    *(const uint4*)(xs + n * 256 + ((kk * 64 + lq * 16) ^ ((n & 7) << 4))));
            }
#pragma unroll
            for (int fn = 0; fn < 2; ++fn) {
                int c = cc4 * 32 + fn * 16 + lr;
                b1[fn] = __builtin_bit_cast(bf16x8, *(const uint4*)(wt1 + c * C_ + kk * 32 + lq * 8));
                b2[fn] = __builtin_bit_cast(bf16x8, *(const uint4*)(wt2 + c * C_ + kk * 32 + lq * 8));
            }
#pragma unroll
            for (int fm = 0; fm < 4; ++fm)
#pragma unroll
                for (int fn = 0; fn < 2; ++fn) {
                    a1[fm][fn] = __builtin_amdgcn_mfma_f32_16x16x32_bf16(afr[fm], b1[fn], a1[fm][fn], 0, 0, 0);
                    a2[fm][fn] = __builtin_amdgcn_mfma_f32_16x16x32_bf16(afr[fm], b2[fn], a2[fm][fn], 0, 0, 0);
                }
        }
        if (nk == 1) __syncthreads();   // prior chunk's slC reads done
        // write Y1T, Y2T chunks [128c][128 n-local], packed 8B
#pragma unroll
        for (int fm = 0; fm < 4; ++fm)
#pragma unroll
            for (int fn = 0; fn < 2; ++fn) {
                int c  = cc4 * 32 + fn * 16 + lr;
                int nl = rn2 * 64 + fm * 16 + lq * 4;
                unsigned short t1[4] __attribute__((aligned(8)));
                unsigned short t2[4] __attribute__((aligned(8)));
#pragma unroll
                for (int r = 0; r < 4; ++r) { t1[r] = f2b(a1[fm][fn][r]); t2[r] = f2b(a2[fm][fn][r]); }
                *(uint2*)(slC1 + c * 256 + ((nl * 2) ^ ((c & 7) << 4))) = *(const uint2*)t1;
                *(uint2*)(slC2 + c * 256 + ((nl * 2) ^ ((c & 7) << 4))) = *(const uint2*)t2;
            }
        __syncthreads();
        // accO += Y1Tc·adj[chunk,:] + Y2Tc·adj2[chunk,:]  (128-MFMA stretch)
#pragma unroll
        for (int kk = 0; kk < 4; ++kk) {
            bf16x8 afr[4], bfr[4];
#pragma unroll
            for (int fm = 0; fm < 4; ++fm) {
                int c = wct * 64 + fm * 16 + lr;
                afr[fm] = __builtin_bit_cast(bf16x8,
                    *(const uint4*)(slC1 + c * 256 + ((kk * 64 + lq * 16) ^ ((c & 7) << 4))));
            }
#pragma unroll
            for (int fn = 0; fn < 4; ++fn) {
                int n = wnt * 64 + fn * 16 + lr;
                bfr[fn] = __builtin_bit_cast(bf16x8,
                    *(const uint4*)(adj + n * N_ + nk * 128 + kk * 32 + lq * 8));
            }
#pragma unroll
            for (int fm = 0; fm < 4; ++fm)
#pragma unroll
                for (int fn = 0; fn < 4; ++fn)
                    accO[fm][fn] = __builtin_amdgcn_mfma_f32_16x16x32_bf16(afr[fm], bfr[fn], accO[fm][fn], 0, 0, 0);
        }
#pragma unroll
        for (int kk = 0; kk < 4; ++kk) {
            bf16x8 afr[4], bfr[4];
#pragma unroll
            for (int fm = 0; fm < 4; ++fm) {
                int c = wct * 64 + fm * 16 + lr;
                afr[fm] = __builtin_bit_cast(bf16x8,
                    *(const uint4*)(slC2 + c * 256 + ((kk * 64 + lq * 16) ^ ((c & 7) << 4))));
            }
#pragma unroll
            for (int fn = 0; fn < 4; ++fn) {
                int n = wnt * 64 + fn * 16 + lr;
                bfr[fn] = __builtin_bit_cast(bf16x8,
                    *(const uint4*)(adj2 + n * N_ + nk * 128 + kk * 32 + lq * 8));
            }
#pragma unroll
            for (int fm = 0; fm < 4; ++fm)
#pragma unroll
                for (int fn = 0; fn < 4; ++fn)
                    accO[fm][fn] = __builtin_amdgcn_mfma_f32_16x16x32_bf16(afr[fm], bfr[fn], accO[fm][fn], 0, 0, 0);
        }
    }

    // ---- store: D[c][n] frag = 4 consecutive c at one n -> float4
#pragma unroll
    for (int fm = 0; fm < 4; ++fm) {
        int c0 = wct * 64 + fm * 16 + lq * 4;
#pragma unroll
        for (int fn = 0; fn < 4; ++fn) {
            int n = wnt * 64 + fn * 16 + lr;
            *(float4*)(og + n * C_ + c0) = __builtin_bit_cast(float4, accO[fm][fn]);
        }
    }
}

// ---------------------------------------------------------------------------
// Kernel 2 (fallback): used only if ws too small for x'.
// ---------------------------------------------------------------------------
extern "C" __global__ __launch_bounds__(512, 2) void k_main_fb(
    const float* __restrict__ timep,
    const float* __restrict__ frep,
    const unsigned short* __restrict__ adj,
    const float* __restrict__ fused_ws,
    const float* __restrict__ scale_tp,
    const float* __restrict__ scale_fp,
    const unsigned short* __restrict__ wtp,
    const float* __restrict__ btp,
    const float* __restrict__ bfp,
    float* __restrict__ outp)
{
    extern __shared__ char smem[];
    char* cb = smem + 65536;
    float* fused_s = (float*)cb;
    const int t  = threadIdx.x;
    const int b  = blockIdx.x;
    const int br = blockIdx.y;
    const float* xg = (br ? frep : timep) + (size_t)b * (N_ * C_);
    const unsigned short* wt0 = wtp + br * (3 * C_ * C_);
    const unsigned short* wt1 = wt0 + C_ * C_;
    const unsigned short* wt2 = wt0 + 2 * C_ * C_;
    const float* bias = br ? bfp : btp;
    float* og = outp + (size_t)br * B_ * N_ * C_ + (size_t)b * (N_ * C_);
    const float scale = (br ? scale_fp : scale_tp)[0];

    fused_s[t] = fused_ws[(size_t)b * (L_ * C_) + t];
    __syncthreads();
    {
        const int n = t >> 1, h = t & 1;
        float xv[64];
        const float4* xr = (const float4*)(xg + n * C_ + h * 64);
#pragma unroll
        for (int i4 = 0; i4 < 16; ++i4) {
            float4 u = xr[i4];
            xv[i4 * 4 + 0] = u.x; xv[i4 * 4 + 1] = u.y;
            xv[i4 * 4 + 2] = u.z; xv[i4 * 4 + 3] = u.w;
        }
        float s0 = 0, s1 = 0, s2 = 0, s3 = 0;
#pragma unroll
        for (int k = 0; k < 64; ++k) {
            int c = h * 64 + k; float x = xv[k];
            s0 += x * fused_s[c];          s1 += x * fused_s[C_ + c];
            s2 += x * fused_s[2 * C_ + c]; s3 += x * fused_s[3 * C_ + c];
        }
        s0 += __shfl_xor(s0, 1); s1 += __shfl_xor(s1, 1);
        s2 += __shfl_xor(s2, 1); s3 += __shfl_xor(s3, 1);
        const float isc = 0.0883883476483184f;
        s0 *= isc; s1 *= isc; s2 *= isc; s3 *= isc;
        float m = fmaxf(fmaxf(s0, s1), fmaxf(s2, s3));
        float p0 = __expf(s0 - m), p1 = __expf(s1 - m), p2 = __expf(s2 - m), p3 = __expf(s3 - m);
        float inv = scale / (p0 + p1 + p2 + p3);
        p0 *= inv; p1 *= inv; p2 *= inv; p3 *= inv;
#pragma unroll
        for (int ci = 0; ci < 8; ++ci) {
            unsigned short ov[8] __attribute__((aligned(16)));
#pragma unroll
            for (int i = 0; i < 8; ++i) {
                int k = ci * 8 + i; int c = h * 64 + k;
                float v = xv[k] + p0 * fused_s[c] + p1 * fused_s[C_ + c]
                        + p2 * fused_s[2 * C_ + c] + p3 * fused_s[3 * C_ + c];
                ov[i] = f2b(v);
            }
            int chunk = h * 8 + ci;
            *(uint4*)(smem + n * 256 + ((chunk * 16) ^ ((n & 7) << 4))) = *(const uint4*)ov;
        }
    }
    __syncthreads();

    const int w = t >> 6, lane = t & 63;
    const int lr = lane & 15, lq = lane >> 4;
    const int wrn = w >> 1, wcc = w & 1;
    const int wct = w >> 2, wnt = w & 3;
    const int rn  = w >> 1;

    f32x4 acc[4][4];
#pragma unroll
    for (int fm = 0; fm < 4; ++fm)
#pragma unroll
        for (int fn = 0; fn < 4; ++fn) acc[fm][fn] = f32x4{0.f, 0.f, 0.f, 0.f};
#pragma unroll
    for (int kk = 0; kk < 4; ++kk) {
        bf16x8 afr[4], bfr[4];
#pragma unroll
        for (int fm = 0; fm < 4; ++fm) {
            int n = wrn * 64 + fm * 16 + lr;
            afr[fm] = __builtin_bit_cast(bf16x8,
                *(const uint4*)(smem + n * 256 + ((kk * 64 + lq * 16) ^ ((n & 7) << 4))));
        }
#pragma unroll
        for (int fn = 0; fn < 4; ++fn) {
            int d = wcc * 64 + fn * 16 + lr;
            bfr[fn] = __builtin_bit_cast(bf16x8, *(const uint4*)(wt1 + d * C_ + kk * 32 + lq * 8));
        }
#pragma unroll
        for (int fm = 0; fm < 4; ++fm)
#pragma unroll
            for (int fn = 0; fn < 4; ++fn)
                acc[fm][fn] = __builtin_amdgcn_mfma_f32_16x16x32_bf16(afr[fm], bfr[fn], acc[fm][fn], 0, 0, 0);
    }
    for (int ch = 0; ch < 4; ++ch) {
        f32x4 acc2[4];
#pragma unroll
        for (int fn = 0; fn < 4; ++fn) acc2[fn] = f32x4{0.f, 0.f, 0.f, 0.f};
#pragma unroll
        for (int kk = 0; kk < 4; ++kk) {
            int n = ch * 64 + rn * 16 + lr;
            bf16x8 a = __builtin_bit_cast(bf16x8,
                *(const uint4*)(smem + n * 256 + ((kk * 64 + lq * 16) ^ ((n & 7) << 4))));
#pragma unroll
            for (int fn = 0; fn < 4; ++fn) {
                int d = wcc * 64 + fn * 16 + lr;
                bf16x8 bfr = __builtin_bit_cast(bf16x8, *(const uint4*)(wt2 + d * C_ + kk * 32 + lq * 8));
                acc2[fn] = __builtin_amdgcn_mfma_f32_16x16x32_bf16(a, bfr, acc2[fn], 0, 0, 0);
            }
        }
#pragma unroll
        for (int fn = 0; fn < 4; ++fn) {
            int c   = wcc * 64 + fn * 16 + lr;
            int n0l = rn * 16 + lq * 4;
            f32x4 a = acc2[fn];
            unsigned short tmp[4] __attribute__((aligned(8)));
#pragma unroll
            for (int r = 0; r < 4; ++r) tmp[r] = f2b(a[r]);
            *(uint2*)(cb + c * 128 + ((n0l * 2) ^ ((c & 7) << 4))) = *(const uint2*)tmp;
        }
        __syncthreads();
#pragma unroll
        for (int kk = 0; kk < 2; ++kk) {
            bf16x8 afr[4], bfr[4];
#pragma unroll
            for (int fm = 0; fm < 4; ++fm) {
                int n = wrn * 64 + fm * 16 + lr;
                afr[fm] = __builtin_bit_cast(bf16x8,
                    *(const uint4*)(adj + n * N_ + ch * 64 + kk * 32 + lq * 8));
            }
#pragma unroll
            for (int fn = 0; fn < 4; ++fn) {
                int c = wcc * 64 + fn * 16 + lr;
                bfr[fn] = __builtin_bit_cast(bf16x8,
                    *(const uint4*)(cb + c * 128 + ((kk * 64 + lq * 16) ^ ((c & 7) << 4))));
            }
#pragma unroll
            for (int fm = 0; fm < 4; ++fm)
#pragma unroll
                for (int fn = 0; fn < 4; ++fn)
                    acc[fm][fn] = __builtin_amdgcn_mfma_f32_16x16x32_bf16(afr[fm], bfr[fn], acc[fm][fn], 0, 0, 0);
        }
        __syncthreads();
    }
    uint2 Zb[4][4];
#pragma unroll
    for (int fm = 0; fm < 4; ++fm)
#pragma unroll
        for (int fn = 0; fn < 4; ++fn) {
            f32x4 a = acc[fm][fn];
            unsigned short tmp[4] __attribute__((aligned(8)));
#pragma unroll
            for (int r = 0; r < 4; ++r) tmp[r] = f2b(a[r]);
            Zb[fm][fn] = *(const uint2*)tmp;
        }
    f32x4 accO[4][4];
#pragma unroll
    for (int fm = 0; fm < 4; ++fm) {
        float4 b4 = *(const float4*)(bias + wct * 64 + fm * 16 + lq * 4);
#pragma unroll
        for (int fn = 0; fn < 4; ++fn) accO[fm][fn] = f32x4{b4.x, b4.y, b4.z, b4.w};
    }
#pragma unroll
    for (int kk = 0; kk < 4; ++kk) {
        bf16x8 afr[4], bfr[4];
#pragma unroll
        for (int fm = 0; fm < 4; ++fm) {
            int d = wct * 64 + fm * 16 + lr;
            afr[fm] = __builtin_bit_cast(bf16x8, *(const uint4*)(wt0 + d * C_ + kk * 32 + lq * 8));
        }
#pragma unroll
        for (int fn = 0; fn < 4; ++fn) {
            int n = wnt * 64 + fn * 16 + lr;
            bfr[fn] = __builtin_bit_cast(bf16x8,
                *(const uint4*)(smem + n * 256 + ((kk * 64 + lq * 16) ^ ((n & 7) << 4))));
        }
#pragma unroll
        for (int fm = 0; fm < 4; ++fm)
#pragma unroll
            for (int fn = 0; fn < 4; ++fn)
                accO[fm][fn] = __builtin_amdgcn_mfma_f32_16x16x32_bf16(afr[fm], bfr[fn], accO[fm][fn], 0, 0, 0);
    }
    for (int ch = 0; ch < 4; ++ch) {
        if (wrn == ch) {
#pragma unroll
            for (int fm = 0; fm < 4; ++fm)
#pragma unroll
                for (int fn = 0; fn < 4; ++fn) {
                    int c   = wcc * 64 + fn * 16 + lr;
                    int n0l = fm * 16 + lq * 4;
                    *(uint2*)(cb + c * 128 + ((n0l * 2) ^ ((c & 7) << 4))) = Zb[fm][fn];
                }
        }
        __syncthreads();
#pragma unroll
        for (int kk = 0; kk < 2; ++kk) {
            bf16x8 afr[4], bfr[4];
#pragma unroll
            for (int fm = 0; fm < 4; ++fm) {
                int c = wct * 64 + fm * 16 + lr;
                afr[fm] = __builtin_bit_cast(bf16x8,
                    *(const uint4*)(cb + c * 128 + ((kk * 64 + lq * 16) ^ ((c & 7) << 4))));
            }
#pragma unroll
            for (int fn = 0; fn < 4; ++fn) {
                int n = wnt * 64 + fn * 16 + lr;
                bfr[fn] = __builtin_bit_cast(bf16x8,
                    *(const uint4*)(adj + n * N_ + ch * 64 + kk * 32 + lq * 8));
            }
#pragma unroll
            for (int fm = 0; fm < 4; ++fm)
#pragma unroll
                for (int fn = 0; fn < 4; ++fn)
                    accO[fm][fn] = __builtin_amdgcn_mfma_f32_16x16x32_bf16(afr[fm], bfr[fn], accO[fm][fn], 0, 0, 0);
        }
        __syncthreads();
    }
#pragma unroll
    for (int fm = 0; fm < 4; ++fm) {
        int c0 = wct * 64 + fm * 16 + lq * 4;
#pragma unroll
        for (int fn = 0; fn < 4; ++fn) {
            int n = wnt * 64 + fn * 16 + lr;
            *(float4*)(og + n * C_ + c0) = __builtin_bit_cast(float4, accO[fm][fn]);
        }
    }
}

// ---------------------------------------------------------------------------
extern "C" void kernel_launch(void* const* d_in, const int* in_sizes, int n_in,
                              void* d_out, int out_size, void* d_ws, size_t ws_size,
                              hipStream_t stream)
{
    const float* timep = (const float*)d_in[0];
    const float* frep  = (const float*)d_in[1];
    const float* adjf  = (const float*)d_in[2];
    const float* lat   = (const float*)d_in[3];
    const float* sct   = (const float*)d_in[4];
    const float* scf   = (const float*)d_in[5];
    const float* Wt    = (const float*)d_in[6];
    const float* bt    = (const float*)d_in[7];
    const float* Wf    = (const float*)d_in[8];
    const float* bf    = (const float*)d_in[9];
    float* outp = (float*)d_out;

    float* fused_ws         = (float*)d_ws;                                        // 2 MB
    unsigned short* wtp     = (unsigned short*)((char*)d_ws + 2097152);            // 192 KB
    unsigned short* adj_bs  = (unsigned short*)((char*)d_ws + 2097152 + 196608);   // 128 KB
    unsigned short* adj2_bs = (unsigned short*)((char*)d_ws + 2097152 + 327680);   // 128 KB
    unsigned short* xpws    = (unsigned short*)((char*)d_ws + 4194304);            // 128 MB

    const size_t need = 4194304ull + 134217728ull;
    const int fast = (ws_size >= need) ? 1 : 0;

    hipFuncSetAttribute((const void*)k_latent,  hipFuncAttributeMaxDynamicSharedMemorySize, 145408);
    hipFuncSetAttribute((const void*)k_cheb,    hipFuncAttributeMaxDynamicSharedMemorySize, 131072);
    hipFuncSetAttribute((const void*)k_main_fb, hipFuncAttributeMaxDynamicSharedMemorySize, 81920);

    k_prep<<<640, 256, 0, stream>>>(Wt, Wf, adjf, wtp, adj_bs);
    if (fast) k_adj2<<<256, 256, 0, stream>>>(adjf, adj2_bs);
    k_latent<<<1024, 512, 145408, stream>>>(timep, frep, lat, sct, scf,
                                            fused_ws, xpws, fast);
    if (fast) {
        k_cheb<<<dim3(1024, 2), 512, 131072, stream>>>(adj_bs, adj2_bs, wtp, bt, bf, xpws, outp);
    } else {
        k_main_fb<<<dim3(1024, 2), 512, 81920, stream>>>(timep, frep, adj_bs, fused_ws,
                                                         sct, scf, wtp, bt, bf, outp);
    }
}

// Round 12
// 438.487 us; speedup vs baseline: 1.0453x; 1.0453x over previous
//
#include <hip/hip_runtime.h>

#define B_ 1024
#define N_ 256
#define C_ 128
#define L_ 4

typedef __bf16 bf16x8 __attribute__((ext_vector_type(8)));
typedef float f32x4 __attribute__((ext_vector_type(4)));

__device__ __forceinline__ float b2f(unsigned short u) {
    union { unsigned int i; float f; } v; v.i = ((unsigned int)u) << 16; return v.f;
}
__device__ __forceinline__ unsigned short f2b(float f) {
    union { float f; unsigned int i; } v; v.f = f;
    unsigned int u = v.i;
    u = (u + 0x7FFFu + ((u >> 16) & 1u)) >> 16;
    return (unsigned short)u;
}

// ---------------------------------------------------------------------------
// Kernel 0: prep (bf16): wtp[br][0]=(W0-W2+I)^T, [1]=W1^T, [2]=(2W2)^T; adj bf16
// ---------------------------------------------------------------------------
extern "C" __global__ __launch_bounds__(256) void k_prep(
    const float* __restrict__ Wt,
    const float* __restrict__ Wf,
    const float* __restrict__ adjf,
    unsigned short* __restrict__ wtp,
    unsigned short* __restrict__ adj_bs)
{
    int i = blockIdx.x * 256 + threadIdx.x;      // [0, 163840)
    if (i < 98304) {
        int br = i / 49152;
        int r  = i - br * 49152;
        int mat = r >> 14;
        int r2  = r & 16383;
        int d = r2 >> 7, c = r2 & 127;
        const float* S = br ? Wf : Wt;
        float v;
        if (mat == 0) {
            v = S[c * 128 + d] - S[2 * 16384 + c * 128 + d] + (c == d ? 1.0f : 0.0f);
        } else if (mat == 1) {
            v = S[16384 + c * 128 + d];
        } else {
            v = 2.0f * S[2 * 16384 + c * 128 + d];
        }
        wtp[i] = f2b(v);
    } else {
        int j = i - 98304;                        // [0, 65536)
        adj_bs[j] = f2b(adjf[j]);
    }
}

// ---------------------------------------------------------------------------
// Kernel 1: latent attention (+ x' production to ws). 1024 threads (16 waves)
// for issue-width: load/copyout 2x parallel, wsum 128 iters/wave, scores and
// x' phases split per half-row with shfl_xor(1) combine. Tiny per-thread
// state -> safe under the 1024-thread 64-VGPR cap (no MFMA accs here).
// LDS: tile 128K + scr 8K + part 8K + lat 2K = 146K.
// ---------------------------------------------------------------------------
extern "C" __global__ __launch_bounds__(1024) void k_latent(
    const float* __restrict__ timep,
    const float* __restrict__ frep,
    const float* __restrict__ latents,
    const float* __restrict__ scale_tp,
    const float* __restrict__ scale_fp,
    float* __restrict__ fused_out,
    unsigned short* __restrict__ xpws,
    int do_xp)
{
    extern __shared__ char smem[];
    float* scr  = (float*)(smem + 131072);            // [4][512] scores
    float* part = (float*)(smem + 131072 + 8192);     // [4][4][128] partials
    float* lat  = (float*)(smem + 131072 + 16384);    // [4][128] latents -> fused
    const int t = threadIdx.x;
    const int b = blockIdx.x;
    const float4* tg = (const float4*)(timep + (size_t)b * (N_ * C_));
    const float4* fg = (const float4*)(frep  + (size_t)b * (N_ * C_));
#pragma unroll
    for (int i = 0; i < 16; ++i) {
        int ch = i * 1024 + t;                    // [0,16384)
        const float4* p = (ch < 8192) ? (tg + ch) : (fg + (ch - 8192));
        float4 u = *p;
        int row = ch >> 5, c4 = ch & 31;
        unsigned short o[4] __attribute__((aligned(8)));
        o[0] = f2b(u.x); o[1] = f2b(u.y); o[2] = f2b(u.z); o[3] = f2b(u.w);
        *(uint2*)(smem + row * 256 + ((c4 * 8) ^ ((row & 7) << 4))) = *(const uint2*)o;
    }
    if (t < 512) lat[t] = latents[t];
    __syncthreads();

    const float isc = 0.0883883476483184f;   // 1/sqrt(128)
    const int j = t >> 1, h = t & 1;         // row, half (pair = adjacent lanes)
    {   // scores vs latents: half-row partials, shfl combine
        float s0 = 0, s1 = 0, s2 = 0, s3 = 0;
#pragma unroll
        for (int ci = 0; ci < 8; ++ci) {
            int cc = h * 8 + ci;
            uint4 u = *(const uint4*)(smem + j * 256 + ((cc * 16) ^ ((j & 7) << 4)));
            const unsigned short* xb = (const unsigned short*)&u;
#pragma unroll
            for (int i = 0; i < 8; ++i) {
                float xv = b2f(xb[i]); int c = cc * 8 + i;
                s0 += xv * lat[c];           s1 += xv * lat[C_ + c];
                s2 += xv * lat[2 * C_ + c];  s3 += xv * lat[3 * C_ + c];
            }
        }
        s0 += __shfl_xor(s0, 1); s1 += __shfl_xor(s1, 1);
        s2 += __shfl_xor(s2, 1); s3 += __shfl_xor(s3, 1);
        if (h == 0) {
            scr[j] = s0 * isc; scr[512 + j] = s1 * isc;
            scr[1024 + j] = s2 * isc; scr[1536 + j] = s3 * isc;
        }
    }
    __syncthreads();

    const int w = t >> 6, lane = t & 63;
    if (w < 4) {   // softmax over 512, wave w owns latent l=w
        float v[8]; float m = -1e30f;
#pragma unroll
        for (int i = 0; i < 8; ++i) { v[i] = scr[w * 512 + lane * 8 + i]; m = fmaxf(m, v[i]); }
#pragma unroll
        for (int off = 32; off >= 1; off >>= 1) m = fmaxf(m, __shfl_xor(m, off));
        float s = 0;
#pragma unroll
        for (int i = 0; i < 8; ++i) { v[i] = __expf(v[i] - m); s += v[i]; }
#pragma unroll
        for (int off = 32; off >= 1; off >>= 1) s += __shfl_xor(s, off);
        float inv = 1.0f / s;
#pragma unroll
        for (int i = 0; i < 8; ++i) scr[w * 512 + lane * 8 + i] = v[i] * inv;
    }
    __syncthreads();
    {   // weighted sum: wave w: latent l=w>>2, quarter jq=w&3; lane owns 2 ch
        const int l = w >> 2, jq = w & 3;
        float f0 = 0.f, f1 = 0.f;
        for (int jj = jq * 128; jj < jq * 128 + 128; ++jj) {
            float p = scr[l * 512 + jj];
            unsigned int pr = *(const unsigned int*)(smem + jj * 256 + ((lane * 4) ^ ((jj & 7) << 4)));
            f0 += p * b2f((unsigned short)(pr & 0xFFFFu));
            f1 += p * b2f((unsigned short)(pr >> 16));
        }
        part[(l * 4 + jq) * 128 + lane * 2]     = f0;
        part[(l * 4 + jq) * 128 + lane * 2 + 1] = f1;
    }
    __syncthreads();
    if (t < 512) {
        int l = t >> 7, c = t & 127;
        float f = part[(l * 4 + 0) * 128 + c] + part[(l * 4 + 1) * 128 + c]
                + part[(l * 4 + 2) * 128 + c] + part[(l * 4 + 3) * 128 + c];
        lat[l * 128 + c] = f;
        fused_out[(size_t)b * 512 + l * 128 + c] = f;
    }
    __syncthreads();

    if (!do_xp) return;

    // ---- x' phase: pair (j,h) owns row j; half-row partial + shfl combine
    {
        const int brx = j >> 8;
        const float scale = brx ? scale_fp[0] : scale_tp[0];
        float s0 = 0, s1 = 0, s2 = 0, s3 = 0;
#pragma unroll
        for (int ci = 0; ci < 8; ++ci) {
            int cc = h * 8 + ci;
            uint4 u = *(const uint4*)(smem + j * 256 + ((cc * 16) ^ ((j & 7) << 4)));
            const unsigned short* xb = (const unsigned short*)&u;
#pragma unroll
            for (int i = 0; i < 8; ++i) {
                float xv = b2f(xb[i]); int c = cc * 8 + i;
                s0 += xv * lat[c];           s1 += xv * lat[C_ + c];
                s2 += xv * lat[2 * C_ + c];  s3 += xv * lat[3 * C_ + c];
            }
        }
        s0 += __shfl_xor(s0, 1); s1 += __shfl_xor(s1, 1);
        s2 += __shfl_xor(s2, 1); s3 += __shfl_xor(s3, 1);
        s0 *= isc; s1 *= isc; s2 *= isc; s3 *= isc;
        float m = fmaxf(fmaxf(s0, s1), fmaxf(s2, s3));
        float p0 = __expf(s0 - m), p1 = __expf(s1 - m), p2 = __expf(s2 - m), p3 = __expf(s3 - m);
        float inv = scale / (p0 + p1 + p2 + p3);
        p0 *= inv; p1 *= inv; p2 *= inv; p3 *= inv;
#pragma unroll
        for (int ci = 0; ci < 8; ++ci) {
            int cc = h * 8 + ci;
            char* slot = smem + j * 256 + ((cc * 16) ^ ((j & 7) << 4));
            uint4 u = *(const uint4*)slot;
            const unsigned short* xb = (const unsigned short*)&u;
            unsigned short ov[8] __attribute__((aligned(16)));
#pragma unroll
            for (int i = 0; i < 8; ++i) {
                int c = cc * 8 + i;
                float v = b2f(xb[i]) + p0 * lat[c] + p1 * lat[C_ + c]
                        + p2 * lat[2 * C_ + c] + p3 * lat[3 * C_ + c];
                ov[i] = f2b(v);
            }
            *(uint4*)slot = *(const uint4*)ov;
        }
    }
    __syncthreads();

    // ---- coalesced copy-out: x'ws[(br*1024+b)*256 + n][c]
    {
#pragma unroll
        for (int i = 0; i < 8; ++i) {
            int ch = i * 1024 + t;                // 8192 chunks of 16B
            int row = ch >> 4, cj = ch & 15;
            uint4 u = *(const uint4*)(smem + row * 256 + ((cj * 16) ^ ((row & 7) << 4)));
            size_t off = (((size_t)(row >> 8) * B_ + b) * N_ + (row & 255)) * C_ + cj * 8;
            *(uint4*)(xpws + off) = u;
        }
    }
}

// ---------------------------------------------------------------------------
// Kernel 2 (fast, R10-proven): block=(b,br), 8 waves, full C. LDS 128KB:
//   xs [256n][256B] swz  @0      : x' staged once (A/B for all W-GEMMs)
//   slA [128][256B] swz  @64K    : W1 -> Y2T/ZT n-chunks (128c x 128n bf16)
//   slB [128][256B] swz  @96K    : W2 -> W0
// Only adj fragments stream from global (L2-hot).
// ---------------------------------------------------------------------------
extern "C" __global__ __launch_bounds__(512, 1) void k_cheb(
    const unsigned short* __restrict__ adj,       // bf16 [256][256], symmetric
    const unsigned short* __restrict__ wtp,
    const float* __restrict__ btp,
    const float* __restrict__ bfp,
    const unsigned short* __restrict__ xpws,
    float* __restrict__ outp)
{
    extern __shared__ char smem[];
    char* xs  = smem;            // 64KB
    char* slA = smem + 65536;    // 32KB
    char* slB = smem + 98304;    // 32KB
    const int t  = threadIdx.x;
    const int b  = blockIdx.x;
    const int br = blockIdx.y;
    const unsigned short* xw  = xpws + (((size_t)br * B_ + b) * N_) * C_;
    const unsigned short* wt0 = wtp + br * (3 * C_ * C_);
    const unsigned short* wt1 = wt0 + C_ * C_;
    const unsigned short* wt2 = wt0 + 2 * C_ * C_;
    const float* bias = br ? bfp : btp;
    float* og = outp + (size_t)br * B_ * N_ * C_ + (size_t)b * (N_ * C_);

    // ---- stage x' (4096 x 16B), W1, W2 (2048 x 16B each), swizzled dests
#pragma unroll
    for (int j = 0; j < 8; ++j) {
        int ch = j * 512 + t; int row = ch >> 4, ck = ch & 15;
        uint4 v = *(const uint4*)(xw + row * C_ + ck * 8);
        *(uint4*)(xs + row * 256 + ((ck * 16) ^ ((row & 7) << 4))) = v;
    }
#pragma unroll
    for (int j = 0; j < 4; ++j) {
        int ch = j * 512 + t; int row = ch >> 4, ck = ch & 15;
        uint4 v1 = *(const uint4*)(wt1 + row * C_ + ck * 8);
        *(uint4*)(slA + row * 256 + ((ck * 16) ^ ((row & 7) << 4))) = v1;
        uint4 v2 = *(const uint4*)(wt2 + row * C_ + ck * 8);
        *(uint4*)(slB + row * 256 + ((ck * 16) ^ ((row & 7) << 4))) = v2;
    }
    __syncthreads();

    const int w = t >> 6, lane = t & 63;
    const int lr = lane & 15, lq = lane >> 4;
    const int wrn = w >> 1, wcc = w & 1;      // D[n][c]: 4 n-bands(64) x 2 c-bands(64)
    const int rn2 = w >> 2, cc4 = w & 3;      // G1c: 2 n-bands(64) x 4 c-bands(32)
    const int wct = w >> 2, wnt = w & 3;      // D[c][n]: 2 c-bands(64) x 4 n-bands(64)

    // ---- G1b: acc = xs·W1   (A xs ds, B W1 slA ds)
    f32x4 acc[4][4];
#pragma unroll
    for (int fm = 0; fm < 4; ++fm)
#pragma unroll
        for (int fn = 0; fn < 4; ++fn) acc[fm][fn] = f32x4{0.f, 0.f, 0.f, 0.f};
#pragma unroll
    for (int kk = 0; kk < 4; ++kk) {
        bf16x8 afr[4], bfr[4];
#pragma unroll
        for (int fm = 0; fm < 4; ++fm) {
            int n = wrn * 64 + fm * 16 + lr;
            afr[fm] = __builtin_bit_cast(bf16x8,
                *(const uint4*)(xs + n * 256 + ((kk * 64 + lq * 16) ^ ((n & 7) << 4))));
        }
#pragma unroll
        for (int fn = 0; fn < 4; ++fn) {
            int c = wcc * 64 + fn * 16 + lr;
            bfr[fn] = __builtin_bit_cast(bf16x8,
                *(const uint4*)(slA + c * 256 + ((kk * 64 + lq * 16) ^ ((c & 7) << 4))));
        }
#pragma unroll
        for (int fm = 0; fm < 4; ++fm)
#pragma unroll
            for (int fn = 0; fn < 4; ++fn)
                acc[fm][fn] = __builtin_amdgcn_mfma_f32_16x16x32_bf16(afr[fm], bfr[fn], acc[fm][fn], 0, 0, 0);
    }

    // ---- n-chunk loop (nk = 0,1): G1c -> Y2T chunk -> G2
    for (int nk = 0; nk < 2; ++nk) {
        f32x4 acc2[4][2];
#pragma unroll
        for (int fm = 0; fm < 4; ++fm)
#pragma unroll
            for (int fn = 0; fn < 2; ++fn) acc2[fm][fn] = f32x4{0.f, 0.f, 0.f, 0.f};
#pragma unroll
        for (int kk = 0; kk < 4; ++kk) {
            bf16x8 afr[4], bfr[2];
#pragma unroll
            for (int fm = 0; fm < 4; ++fm) {
                int n = nk * 128 + rn2 * 64 + fm * 16 + lr;
                afr[fm] = __builtin_bit_cast(bf16x8,
                    *(const uint4*)(xs + n * 256 + ((kk * 64 + lq * 16) ^ ((n & 7) << 4))));
            }
#pragma unroll
            for (int fn = 0; fn < 2; ++fn) {
                int c = cc4 * 32 + fn * 16 + lr;
                bfr[fn] = __builtin_bit_cast(bf16x8,
                    *(const uint4*)(slB + c * 256 + ((kk * 64 + lq * 16) ^ ((c & 7) << 4))));
            }
#pragma unroll
            for (int fm = 0; fm < 4; ++fm)
#pragma unroll
                for (int fn = 0; fn < 2; ++fn)
                    acc2[fm][fn] = __builtin_amdgcn_mfma_f32_16x16x32_bf16(afr[fm], bfr[fn], acc2[fm][fn], 0, 0, 0);
        }
        __syncthreads();   // prior slA readers (G1b / previous G2) done
        // write Y2T chunk [128c][128n-local]
#pragma unroll
        for (int fm = 0; fm < 4; ++fm)
#pragma unroll
            for (int fn = 0; fn < 2; ++fn) {
                int c  = cc4 * 32 + fn * 16 + lr;
                int nl = rn2 * 64 + fm * 16 + lq * 4;
                f32x4 a = acc2[fm][fn];
                unsigned short tmp[4] __attribute__((aligned(8)));
#pragma unroll
                for (int r = 0; r < 4; ++r) tmp[r] = f2b(a[r]);
                *(uint2*)(slA + c * 256 + ((nl * 2) ^ ((c & 7) << 4))) = *(const uint2*)tmp;
            }
        __syncthreads();
        // G2: acc += adj[:, chunk] · Y2c   (A adj global, B slA ds)
#pragma unroll
        for (int kk = 0; kk < 4; ++kk) {
            bf16x8 afr[4], bfr[4];
#pragma unroll
            for (int fm = 0; fm < 4; ++fm) {
                int n = wrn * 64 + fm * 16 + lr;
                afr[fm] = __builtin_bit_cast(bf16x8,
                    *(const uint4*)(adj + n * N_ + nk * 128 + kk * 32 + lq * 8));
            }
#pragma unroll
            for (int fn = 0; fn < 4; ++fn) {
                int c = wcc * 64 + fn * 16 + lr;
                bfr[fn] = __builtin_bit_cast(bf16x8,
                    *(const uint4*)(slA + c * 256 + ((kk * 64 + lq * 16) ^ ((c & 7) << 4))));
            }
#pragma unroll
            for (int fm = 0; fm < 4; ++fm)
#pragma unroll
                for (int fn = 0; fn < 4; ++fn)
                    acc[fm][fn] = __builtin_amdgcn_mfma_f32_16x16x32_bf16(afr[fm], bfr[fn], acc[fm][fn], 0, 0, 0);
        }
    }

    // ---- cvt Z -> bf16 packed (frees acc)
    uint2 Zb[4][4];
#pragma unroll
    for (int fm = 0; fm < 4; ++fm)
#pragma unroll
        for (int fn = 0; fn < 4; ++fn) {
            f32x4 a = acc[fm][fn];
            unsigned short tmp[4] __attribute__((aligned(8)));
#pragma unroll
            for (int r = 0; r < 4; ++r) tmp[r] = f2b(a[r]);
            Zb[fm][fn] = *(const uint2*)tmp;
        }
    __syncthreads();   // G2-c1 slA reads + all W2 (slB) reads done

    // ---- stage W0 -> slB ; write ZT chunk0 -> slA (owners wrn<2)
#pragma unroll
    for (int j = 0; j < 4; ++j) {
        int ch = j * 512 + t; int row = ch >> 4, ck = ch & 15;
        uint4 v0 = *(const uint4*)(wt0 + row * C_ + ck * 8);
        *(uint4*)(slB + row * 256 + ((ck * 16) ^ ((row & 7) << 4))) = v0;
    }
    if (wrn < 2) {
#pragma unroll
        for (int fm = 0; fm < 4; ++fm)
#pragma unroll
            for (int fn = 0; fn < 4; ++fn) {
                int c  = wcc * 64 + fn * 16 + lr;
                int nl = wrn * 64 + fm * 16 + lq * 4;
                *(uint2*)(slA + c * 256 + ((nl * 2) ^ ((c & 7) << 4))) = Zb[fm][fn];
            }
    }
    __syncthreads();

    // ---- G1a: accO = bias + W0''T·xsT  (A slB ds, B xs ds), D[c][n]
    f32x4 accO[4][4];
#pragma unroll
    for (int fm = 0; fm < 4; ++fm) {
        float4 b4 = *(const float4*)(bias + wct * 64 + fm * 16 + lq * 4);
#pragma unroll
        for (int fn = 0; fn < 4; ++fn) accO[fm][fn] = f32x4{b4.x, b4.y, b4.z, b4.w};
    }
#pragma unroll
    for (int kk = 0; kk < 4; ++kk) {
        bf16x8 afr[4], bfr[4];
#pragma unroll
        for (int fm = 0; fm < 4; ++fm) {
            int d = wct * 64 + fm * 16 + lr;
            afr[fm] = __builtin_bit_cast(bf16x8,
                *(const uint4*)(slB + d * 256 + ((kk * 64 + lq * 16) ^ ((d & 7) << 4))));
        }
#pragma unroll
        for (int fn = 0; fn < 4; ++fn) {
            int n = wnt * 64 + fn * 16 + lr;
            bfr[fn] = __builtin_bit_cast(bf16x8,
                *(const uint4*)(xs + n * 256 + ((kk * 64 + lq * 16) ^ ((n & 7) << 4))));
        }
#pragma unroll
        for (int fm = 0; fm < 4; ++fm)
#pragma unroll
            for (int fn = 0; fn < 4; ++fn)
                accO[fm][fn] = __builtin_amdgcn_mfma_f32_16x16x32_bf16(afr[fm], bfr[fn], accO[fm][fn], 0, 0, 0);
    }

    // ---- ZT chunk loop + G3
    for (int nk = 0; nk < 2; ++nk) {
        if (nk == 1) {
            __syncthreads();   // G3-c0 slA reads done
            if (wrn >= 2) {
#pragma unroll
                for (int fm = 0; fm < 4; ++fm)
#pragma unroll
                    for (int fn = 0; fn < 4; ++fn) {
                        int c  = wcc * 64 + fn * 16 + lr;
                        int nl = (wrn - 2) * 64 + fm * 16 + lq * 4;
                        *(uint2*)(slA + c * 256 + ((nl * 2) ^ ((c & 7) << 4))) = Zb[fm][fn];
                    }
            }
        }
        __syncthreads();
        // G3: accO += ZTc · adj[chunk,:]   (A slA ds, B adj global)
#pragma unroll
        for (int kk = 0; kk < 4; ++kk) {
            bf16x8 afr[4], bfr[4];
#pragma unroll
            for (int fm = 0; fm < 4; ++fm) {
                int c = wct * 64 + fm * 16 + lr;
                afr[fm] = __builtin_bit_cast(bf16x8,
                    *(const uint4*)(slA + c * 256 + ((kk * 64 + lq * 16) ^ ((c & 7) << 4))));
            }
#pragma unroll
            for (int fn = 0; fn < 4; ++fn) {
                int n = wnt * 64 + fn * 16 + lr;
                bfr[fn] = __builtin_bit_cast(bf16x8,
                    *(const uint4*)(adj + n * N_ + nk * 128 + kk * 32 + lq * 8));
            }
#pragma unroll
            for (int fm = 0; fm < 4; ++fm)
#pragma unroll
                for (int fn = 0; fn < 4; ++fn)
                    accO[fm][fn] = __builtin_amdgcn_mfma_f32_16x16x32_bf16(afr[fm], bfr[fn], accO[fm][fn], 0, 0, 0);
        }
    }

    // ---- store: D[c][n] frag = 4 consecutive c at one n -> float4
#pragma unroll
    for (int fm = 0; fm < 4; ++fm) {
        int c0 = wct * 64 + fm * 16 + lq * 4;
#pragma unroll
        for (int fn = 0; fn < 4; ++fn) {
            int n = wnt * 64 + fn * 16 + lr;
            *(float4*)(og + n * C_ + c0) = __builtin_bit_cast(float4, accO[fm][fn]);
        }
    }
}

// ---------------------------------------------------------------------------
// Kernel 2 (fallback): used only if ws too small for x'.
// ---------------------------------------------------------------------------
extern "C" __global__ __launch_bounds__(512, 2) void k_main_fb(
    const float* __restrict__ timep,
    const float* __restrict__ frep,
    const unsigned short* __restrict__ adj,
    const float* __restrict__ fused_ws,
    const float* __restrict__ scale_tp,
    const float* __restrict__ scale_fp,
    const unsigned short* __restrict__ wtp,
    const float* __restrict__ btp,
    const float* __restrict__ bfp,
    float* __restrict__ outp)
{
    extern __shared__ char smem[];
    char* cb = smem + 65536;
    float* fused_s = (float*)cb;
    const int t  = threadIdx.x;
    const int b  = blockIdx.x;
    const int br = blockIdx.y;
    const float* xg = (br ? frep : timep) + (size_t)b * (N_ * C_);
    const unsigned short* wt0 = wtp + br * (3 * C_ * C_);
    const unsigned short* wt1 = wt0 + C_ * C_;
    const unsigned short* wt2 = wt0 + 2 * C_ * C_;
    const float* bias = br ? bfp : btp;
    float* og = outp + (size_t)br * B_ * N_ * C_ + (size_t)b * (N_ * C_);
    const float scale = (br ? scale_fp : scale_tp)[0];

    fused_s[t] = fused_ws[(size_t)b * (L_ * C_) + t];
    __syncthreads();
    {
        const int n = t >> 1, h = t & 1;
        float xv[64];
        const float4* xr = (const float4*)(xg + n * C_ + h * 64);
#pragma unroll
        for (int i4 = 0; i4 < 16; ++i4) {
            float4 u = xr[i4];
            xv[i4 * 4 + 0] = u.x; xv[i4 * 4 + 1] = u.y;
            xv[i4 * 4 + 2] = u.z; xv[i4 * 4 + 3] = u.w;
        }
        float s0 = 0, s1 = 0, s2 = 0, s3 = 0;
#pragma unroll
        for (int k = 0; k < 64; ++k) {
            int c = h * 64 + k; float x = xv[k];
            s0 += x * fused_s[c];          s1 += x * fused_s[C_ + c];
            s2 += x * fused_s[2 * C_ + c]; s3 += x * fused_s[3 * C_ + c];
        }
        s0 += __shfl_xor(s0, 1); s1 += __shfl_xor(s1, 1);
        s2 += __shfl_xor(s2, 1); s3 += __shfl_xor(s3, 1);
        const float isc = 0.0883883476483184f;
        s0 *= isc; s1 *= isc; s2 *= isc; s3 *= isc;
        float m = fmaxf(fmaxf(s0, s1), fmaxf(s2, s3));
        float p0 = __expf(s0 - m), p1 = __expf(s1 - m), p2 = __expf(s2 - m), p3 = __expf(s3 - m);
        float inv = scale / (p0 + p1 + p2 + p3);
        p0 *= inv; p1 *= inv; p2 *= inv; p3 *= inv;
#pragma unroll
        for (int ci = 0; ci < 8; ++ci) {
            unsigned short ov[8] __attribute__((aligned(16)));
#pragma unroll
            for (int i = 0; i < 8; ++i) {
                int k = ci * 8 + i; int c = h * 64 + k;
                float v = xv[k] + p0 * fused_s[c] + p1 * fused_s[C_ + c]
                        + p2 * fused_s[2 * C_ + c] + p3 * fused_s[3 * C_ + c];
                ov[i] = f2b(v);
            }
            int chunk = h * 8 + ci;
            *(uint4*)(smem + n * 256 + ((chunk * 16) ^ ((n & 7) << 4))) = *(const uint4*)ov;
        }
    }
    __syncthreads();

    const int w = t >> 6, lane = t & 63;
    const int lr = lane & 15, lq = lane >> 4;
    const int wrn = w >> 1, wcc = w & 1;
    const int wct = w >> 2, wnt = w & 3;
    const int rn  = w >> 1;

    f32x4 acc[4][4];
#pragma unroll
    for (int fm = 0; fm < 4; ++fm)
#pragma unroll
        for (int fn = 0; fn < 4; ++fn) acc[fm][fn] = f32x4{0.f, 0.f, 0.f, 0.f};
#pragma unroll
    for (int kk = 0; kk < 4; ++kk) {
        bf16x8 afr[4], bfr[4];
#pragma unroll
        for (int fm = 0; fm < 4; ++fm) {
            int n = wrn * 64 + fm * 16 + lr;
            afr[fm] = __builtin_bit_cast(bf16x8,
                *(const uint4*)(smem + n * 256 + ((kk * 64 + lq * 16) ^ ((n & 7) << 4))));
        }
#pragma unroll
        for (int fn = 0; fn < 4; ++fn) {
            int d = wcc * 64 + fn * 16 + lr;
            bfr[fn] = __builtin_bit_cast(bf16x8, *(const uint4*)(wt1 + d * C_ + kk * 32 + lq * 8));
        }
#pragma unroll
        for (int fm = 0; fm < 4; ++fm)
#pragma unroll
            for (int fn = 0; fn < 4; ++fn)
                acc[fm][fn] = __builtin_amdgcn_mfma_f32_16x16x32_bf16(afr[fm], bfr[fn], acc[fm][fn], 0, 0, 0);
    }
    for (int ch = 0; ch < 4; ++ch) {
        f32x4 acc2[4];
#pragma unroll
        for (int fn = 0; fn < 4; ++fn) acc2[fn] = f32x4{0.f, 0.f, 0.f, 0.f};
#pragma unroll
        for (int kk = 0; kk < 4; ++kk) {
            int n = ch * 64 + rn * 16 + lr;
            bf16x8 a = __builtin_bit_cast(bf16x8,
                *(const uint4*)(smem + n * 256 + ((kk * 64 + lq * 16) ^ ((n & 7) << 4))));
#pragma unroll
            for (int fn = 0; fn < 4; ++fn) {
                int d = wcc * 64 + fn * 16 + lr;
                bf16x8 bfr = __builtin_bit_cast(bf16x8, *(const uint4*)(wt2 + d * C_ + kk * 32 + lq * 8));
                acc2[fn] = __builtin_amdgcn_mfma_f32_16x16x32_bf16(a, bfr, acc2[fn], 0, 0, 0);
            }
        }
#pragma unroll
        for (int fn = 0; fn < 4; ++fn) {
            int c   = wcc * 64 + fn * 16 + lr;
            int n0l = rn * 16 + lq * 4;
            f32x4 a = acc2[fn];
            unsigned short tmp[4] __attribute__((aligned(8)));
#pragma unroll
            for (int r = 0; r < 4; ++r) tmp[r] = f2b(a[r]);
            *(uint2*)(cb + c * 128 + ((n0l * 2) ^ ((c & 7) << 4))) = *(const uint2*)tmp;
        }
        __syncthreads();
#pragma unroll
        for (int kk = 0; kk < 2; ++kk) {
            bf16x8 afr[4], bfr[4];
#pragma unroll
            for (int fm = 0; fm < 4; ++fm) {
                int n = wrn * 64 + fm * 16 + lr;
                afr[fm] = __builtin_bit_cast(bf16x8,
                    *(const uint4*)(adj + n * N_ + ch * 64 + kk * 32 + lq * 8));
            }
#pragma unroll
            for (int fn = 0; fn < 4; ++fn) {
                int c = wcc * 64 + fn * 16 + lr;
                bfr[fn] = __builtin_bit_cast(bf16x8,
                    *(const uint4*)(cb + c * 128 + ((kk * 64 + lq * 16) ^ ((c & 7) << 4))));
            }
#pragma unroll
            for (int fm = 0; fm < 4; ++fm)
#pragma unroll
                for (int fn = 0; fn < 4; ++fn)
                    acc[fm][fn] = __builtin_amdgcn_mfma_f32_16x16x32_bf16(afr[fm], bfr[fn], acc[fm][fn], 0, 0, 0);
        }
        __syncthreads();
    }
    uint2 Zb[4][4];
#pragma unroll
    for (int fm = 0; fm < 4; ++fm)
#pragma unroll
        for (int fn = 0; fn < 4; ++fn) {
            f32x4 a = acc[fm][fn];
            unsigned short tmp[4] __attribute__((aligned(8)));
#pragma unroll
            for (int r = 0; r < 4; ++r) tmp[r] = f2b(a[r]);
            Zb[fm][fn] = *(const uint2*)tmp;
        }
    f32x4 accO[4][4];
#pragma unroll
    for (int fm = 0; fm < 4; ++fm) {
        float4 b4 = *(const float4*)(bias + wct * 64 + fm * 16 + lq * 4);
#pragma unroll
        for (int fn = 0; fn < 4; ++fn) accO[fm][fn] = f32x4{b4.x, b4.y, b4.z, b4.w};
    }
#pragma unroll
    for (int kk = 0; kk < 4; ++kk) {
        bf16x8 afr[4], bfr[4];
#pragma unroll
        for (int fm = 0; fm < 4; ++fm) {
            int d = wct * 64 + fm * 16 + lr;
            afr[fm] = __builtin_bit_cast(bf16x8, *(const uint4*)(wt0 + d * C_ + kk * 32 + lq * 8));
        }
#pragma unroll
        for (int fn = 0; fn < 4; ++fn) {
            int n = wnt * 64 + fn * 16 + lr;
            bfr[fn] = __builtin_bit_cast(bf16x8,
                *(const uint4*)(smem + n * 256 + ((kk * 64 + lq * 16) ^ ((n & 7) << 4))));
        }
#pragma unroll
        for (int fm = 0; fm < 4; ++fm)
#pragma unroll
            for (int fn = 0; fn < 4; ++fn)
                accO[fm][fn] = __builtin_amdgcn_mfma_f32_16x16x32_bf16(afr[fm], bfr[fn], accO[fm][fn], 0, 0, 0);
    }
    for (int ch = 0; ch < 4; ++ch) {
        if (wrn == ch) {
#pragma unroll
            for (int fm = 0; fm < 4; ++fm)
#pragma unroll
                for (int fn = 0; fn < 4; ++fn) {
                    int c   = wcc * 64 + fn * 16 + lr;
                    int n0l = fm * 16 + lq * 4;
                    *(uint2*)(cb + c * 128 + ((n0l * 2) ^ ((c & 7) << 4))) = Zb[fm][fn];
                }
        }
        __syncthreads();
#pragma unroll
        for (int kk = 0; kk < 2; ++kk) {
            bf16x8 afr[4], bfr[4];
#pragma unroll
            for (int fm = 0; fm < 4; ++fm) {
                int c = wct * 64 + fm * 16 + lr;
                afr[fm] = __builtin_bit_cast(bf16x8,
                    *(const uint4*)(cb + c * 128 + ((kk * 64 + lq * 16) ^ ((c & 7) << 4))));
            }
#pragma unroll
            for (int fn = 0; fn < 4; ++fn) {
                int n = wnt * 64 + fn * 16 + lr;
                bfr[fn] = __builtin_bit_cast(bf16x8,
                    *(const uint4*)(adj + n * N_ + ch * 64 + kk * 32 + lq * 8));
            }
#pragma unroll
            for (int fm = 0; fm < 4; ++fm)
#pragma unroll
                for (int fn = 0; fn < 4; ++fn)
                    accO[fm][fn] = __builtin_amdgcn_mfma_f32_16x16x32_bf16(afr[fm], bfr[fn], accO[fm][fn], 0, 0, 0);
        }
        __syncthreads();
    }
#pragma unroll
    for (int fm = 0; fm < 4; ++fm) {
        int c0 = wct * 64 + fm * 16 + lq * 4;
#pragma unroll
        for (int fn = 0; fn < 4; ++fn) {
            int n = wnt * 64 + fn * 16 + lr;
            *(float4*)(og + n * C_ + c0) = __builtin_bit_cast(float4, accO[fm][fn]);
        }
    }
}

// ---------------------------------------------------------------------------
extern "C" void kernel_launch(void* const* d_in, const int* in_sizes, int n_in,
                              void* d_out, int out_size, void* d_ws, size_t ws_size,
                              hipStream_t stream)
{
    const float* timep = (const float*)d_in[0];
    const float* frep  = (const float*)d_in[1];
    const float* adjf  = (const float*)d_in[2];
    const float* lat   = (const float*)d_in[3];
    const float* sct   = (const float*)d_in[4];
    const float* scf   = (const float*)d_in[5];
    const float* Wt    = (const float*)d_in[6];
    const float* bt    = (const float*)d_in[7];
    const float* Wf    = (const float*)d_in[8];
    const float* bf    = (const float*)d_in[9];
    float* outp = (float*)d_out;

    float* fused_ws        = (float*)d_ws;                                        // 2 MB
    unsigned short* wtp    = (unsigned short*)((char*)d_ws + 2097152);            // 192 KB
    unsigned short* adj_bs = (unsigned short*)((char*)d_ws + 2097152 + 196608);   // 128 KB
    unsigned short* xpws   = (unsigned short*)((char*)d_ws + 4194304);            // 128 MB

    const size_t need = 4194304ull + 134217728ull;
    const int fast = (ws_size >= need) ? 1 : 0;

    hipFuncSetAttribute((const void*)k_latent,  hipFuncAttributeMaxDynamicSharedMemorySize, 149504);
    hipFuncSetAttribute((const void*)k_cheb,    hipFuncAttributeMaxDynamicSharedMemorySize, 131072);
    hipFuncSetAttribute((const void*)k_main_fb, hipFuncAttributeMaxDynamicSharedMemorySize, 81920);

    k_prep<<<640, 256, 0, stream>>>(Wt, Wf, adjf, wtp, adj_bs);
    k_latent<<<1024, 1024, 149504, stream>>>(timep, frep, lat, sct, scf,
                                             fused_ws, xpws, fast);
    if (fast) {
        k_cheb<<<dim3(1024, 2), 512, 131072, stream>>>(adj_bs, wtp, bt, bf, xpws, outp);
    } else {
        k_main_fb<<<dim3(1024, 2), 512, 81920, stream>>>(timep, frep, adj_bs, fused_ws,
                                                         sct, scf, wtp, bt, bf, outp);
    }
}

// Round 13
// 385.400 us; speedup vs baseline: 1.1893x; 1.1377x over previous
//
#include <hip/hip_runtime.h>

#define B_ 1024
#define N_ 256
#define C_ 128
#define L_ 4

typedef __bf16 bf16x8 __attribute__((ext_vector_type(8)));
typedef float f32x4 __attribute__((ext_vector_type(4)));

__device__ __forceinline__ float b2f(unsigned short u) {
    union { unsigned int i; float f; } v; v.i = ((unsigned int)u) << 16; return v.f;
}
__device__ __forceinline__ unsigned short f2b(float f) {
    union { float f; unsigned int i; } v; v.f = f;
    unsigned int u = v.i;
    u = (u + 0x7FFFu + ((u >> 16) & 1u)) >> 16;
    return (unsigned short)u;
}

// ---------------------------------------------------------------------------
// Kernel 0: prep (bf16): wtp[br][0]=(W0-W2+I)^T, [1]=W1^T, [2]=(2W2)^T; adj bf16
// ---------------------------------------------------------------------------
extern "C" __global__ __launch_bounds__(256) void k_prep(
    const float* __restrict__ Wt,
    const float* __restrict__ Wf,
    const float* __restrict__ adjf,
    unsigned short* __restrict__ wtp,
    unsigned short* __restrict__ adj_bs)
{
    int i = blockIdx.x * 256 + threadIdx.x;      // [0, 163840)
    if (i < 98304) {
        int br = i / 49152;
        int r  = i - br * 49152;
        int mat = r >> 14;
        int r2  = r & 16383;
        int d = r2 >> 7, c = r2 & 127;
        const float* S = br ? Wf : Wt;
        float v;
        if (mat == 0) {
            v = S[c * 128 + d] - S[2 * 16384 + c * 128 + d] + (c == d ? 1.0f : 0.0f);
        } else if (mat == 1) {
            v = S[16384 + c * 128 + d];
        } else {
            v = 2.0f * S[2 * 16384 + c * 128 + d];
        }
        wtp[i] = f2b(v);
    } else {
        int j = i - 98304;                        // [0, 65536)
        adj_bs[j] = f2b(adjf[j]);
    }
}

// ---------------------------------------------------------------------------
// Kernel 1: latent attention (+ x' production to ws). 512 threads (R10-proven).
// ---------------------------------------------------------------------------
extern "C" __global__ __launch_bounds__(512) void k_latent(
    const float* __restrict__ timep,
    const float* __restrict__ frep,
    const float* __restrict__ latents,
    const float* __restrict__ scale_tp,
    const float* __restrict__ scale_fp,
    float* __restrict__ fused_out,
    unsigned short* __restrict__ xpws,
    int do_xp)
{
    extern __shared__ char smem[];
    float* scr  = (float*)(smem + 131072);            // [4][512] scores
    float* part = (float*)(smem + 131072 + 8192);     // [4][2][128] partials
    float* lat  = (float*)(smem + 131072 + 12288);    // [4][128] latents -> fused
    const int t = threadIdx.x;
    const int b = blockIdx.x;
    const float4* tg = (const float4*)(timep + (size_t)b * (N_ * C_));
    const float4* fg = (const float4*)(frep  + (size_t)b * (N_ * C_));
#pragma unroll
    for (int i = 0; i < 32; ++i) {
        int ch = i * 512 + t;                     // [0,16384)
        const float4* p = (ch < 8192) ? (tg + ch) : (fg + (ch - 8192));
        float4 u = *p;
        int row = ch >> 5, c4 = ch & 31;
        unsigned short o[4] __attribute__((aligned(8)));
        o[0] = f2b(u.x); o[1] = f2b(u.y); o[2] = f2b(u.z); o[3] = f2b(u.w);
        *(uint2*)(smem + row * 256 + ((c4 * 8) ^ ((row & 7) << 4))) = *(const uint2*)o;
    }
    lat[t & 511] = latents[t & 511];
    __syncthreads();

    const float isc = 0.0883883476483184f;   // 1/sqrt(128)
    {   // scores vs latents: one row per thread
        const int jj = t;
        float s0 = 0, s1 = 0, s2 = 0, s3 = 0;
#pragma unroll
        for (int ci = 0; ci < 16; ++ci) {
            uint4 u = *(const uint4*)(smem + jj * 256 + ((ci * 16) ^ ((jj & 7) << 4)));
            const unsigned short* xb = (const unsigned short*)&u;
#pragma unroll
            for (int i = 0; i < 8; ++i) {
                float xv = b2f(xb[i]); int c = ci * 8 + i;
                s0 += xv * lat[c];           s1 += xv * lat[C_ + c];
                s2 += xv * lat[2 * C_ + c];  s3 += xv * lat[3 * C_ + c];
            }
        }
        scr[jj] = s0 * isc; scr[512 + jj] = s1 * isc;
        scr[1024 + jj] = s2 * isc; scr[1536 + jj] = s3 * isc;
    }
    __syncthreads();

    const int w = t >> 6, lane = t & 63;
    if (w < 4) {   // softmax over 512, wave w owns latent l=w
        float v[8]; float m = -1e30f;
#pragma unroll
        for (int i = 0; i < 8; ++i) { v[i] = scr[w * 512 + lane * 8 + i]; m = fmaxf(m, v[i]); }
#pragma unroll
        for (int off = 32; off >= 1; off >>= 1) m = fmaxf(m, __shfl_xor(m, off));
        float s = 0;
#pragma unroll
        for (int i = 0; i < 8; ++i) { v[i] = __expf(v[i] - m); s += v[i]; }
#pragma unroll
        for (int off = 32; off >= 1; off >>= 1) s += __shfl_xor(s, off);
        float inv = 1.0f / s;
#pragma unroll
        for (int i = 0; i < 8; ++i) scr[w * 512 + lane * 8 + i] = v[i] * inv;
    }
    __syncthreads();
    {   // weighted sum: wave w: latent l=w>>1, half jh=w&1; lane owns 2 channels
        const int l = w >> 1, jh = w & 1;
        float f0 = 0.f, f1 = 0.f;
        for (int j = jh * 256; j < jh * 256 + 256; ++j) {
            float p = scr[l * 512 + j];
            unsigned int pr = *(const unsigned int*)(smem + j * 256 + ((lane * 4) ^ ((j & 7) << 4)));
            f0 += p * b2f((unsigned short)(pr & 0xFFFFu));
            f1 += p * b2f((unsigned short)(pr >> 16));
        }
        part[(l * 2 + jh) * 128 + lane * 2]     = f0;
        part[(l * 2 + jh) * 128 + lane * 2 + 1] = f1;
    }
    __syncthreads();
    {
        int l = t >> 7, c = t & 127;
        float f = part[(l * 2) * 128 + c] + part[(l * 2 + 1) * 128 + c];
        lat[l * 128 + c] = f;
        fused_out[(size_t)b * 512 + l * 128 + c] = f;
    }
    __syncthreads();

    if (!do_xp) return;

    // ---- x' phase: thread owns row j
    {
        const int j = t;
        const int brx = j >> 8;
        const float scale = brx ? scale_fp[0] : scale_tp[0];
        float s0 = 0, s1 = 0, s2 = 0, s3 = 0;
#pragma unroll
        for (int ci = 0; ci < 16; ++ci) {
            uint4 u = *(const uint4*)(smem + j * 256 + ((ci * 16) ^ ((j & 7) << 4)));
            const unsigned short* xb = (const unsigned short*)&u;
#pragma unroll
            for (int i = 0; i < 8; ++i) {
                float xv = b2f(xb[i]); int c = ci * 8 + i;
                s0 += xv * lat[c];           s1 += xv * lat[C_ + c];
                s2 += xv * lat[2 * C_ + c];  s3 += xv * lat[3 * C_ + c];
            }
        }
        s0 *= isc; s1 *= isc; s2 *= isc; s3 *= isc;
        float m = fmaxf(fmaxf(s0, s1), fmaxf(s2, s3));
        float p0 = __expf(s0 - m), p1 = __expf(s1 - m), p2 = __expf(s2 - m), p3 = __expf(s3 - m);
        float inv = scale / (p0 + p1 + p2 + p3);
        p0 *= inv; p1 *= inv; p2 *= inv; p3 *= inv;
#pragma unroll
        for (int ci = 0; ci < 16; ++ci) {
            char* slot = smem + j * 256 + ((ci * 16) ^ ((j & 7) << 4));
            uint4 u = *(const uint4*)slot;
            const unsigned short* xb = (const unsigned short*)&u;
            unsigned short ov[8] __attribute__((aligned(16)));
#pragma unroll
            for (int i = 0; i < 8; ++i) {
                int c = ci * 8 + i;
                float v = b2f(xb[i]) + p0 * lat[c] + p1 * lat[C_ + c]
                        + p2 * lat[2 * C_ + c] + p3 * lat[3 * C_ + c];
                ov[i] = f2b(v);
            }
            *(uint4*)slot = *(const uint4*)ov;
        }
    }
    __syncthreads();

    // ---- coalesced copy-out: x'ws[(br*1024+b)*256 + n][c]
    {
#pragma unroll
        for (int i = 0; i < 16; ++i) {
            int ch = i * 512 + t;                 // 8192 chunks of 16B
            int row = ch >> 4, cj = ch & 15;
            uint4 u = *(const uint4*)(smem + row * 256 + ((cj * 16) ^ ((row & 7) << 4)));
            size_t off = (((size_t)(row >> 8) * B_ + b) * N_ + (row & 255)) * C_ + cj * 8;
            *(uint4*)(xpws + off) = u;
        }
    }
}

// ---------------------------------------------------------------------------
// Kernel 2 (fast, R10 + adj prefetch): block=(b,br), 8 waves. LDS 128KB:
//   xs [256n][256B] swz @0 ; slA @64K: W1 -> Y2T/ZT chunks ; slB @96K: W2 -> W0
// adj fragments for G2/G3 kk<2 are prefetched into regs BEFORE the phase
// barriers so L2 latency drains during the barrier, not inside the MFMA phase.
// ---------------------------------------------------------------------------
extern "C" __global__ __launch_bounds__(512, 1) void k_cheb(
    const unsigned short* __restrict__ adj,       // bf16 [256][256], symmetric
    const unsigned short* __restrict__ wtp,
    const float* __restrict__ btp,
    const float* __restrict__ bfp,
    const unsigned short* __restrict__ xpws,
    float* __restrict__ outp)
{
    extern __shared__ char smem[];
    char* xs  = smem;            // 64KB
    char* slA = smem + 65536;    // 32KB
    char* slB = smem + 98304;    // 32KB
    const int t  = threadIdx.x;
    const int b  = blockIdx.x;
    const int br = blockIdx.y;
    const unsigned short* xw  = xpws + (((size_t)br * B_ + b) * N_) * C_;
    const unsigned short* wt0 = wtp + br * (3 * C_ * C_);
    const unsigned short* wt1 = wt0 + C_ * C_;
    const unsigned short* wt2 = wt0 + 2 * C_ * C_;
    const float* bias = br ? bfp : btp;
    float* og = outp + (size_t)br * B_ * N_ * C_ + (size_t)b * (N_ * C_);

    // ---- stage x' (4096 x 16B), W1, W2 (2048 x 16B each), swizzled dests
#pragma unroll
    for (int j = 0; j < 8; ++j) {
        int ch = j * 512 + t; int row = ch >> 4, ck = ch & 15;
        uint4 v = *(const uint4*)(xw + row * C_ + ck * 8);
        *(uint4*)(xs + row * 256 + ((ck * 16) ^ ((row & 7) << 4))) = v;
    }
#pragma unroll
    for (int j = 0; j < 4; ++j) {
        int ch = j * 512 + t; int row = ch >> 4, ck = ch & 15;
        uint4 v1 = *(const uint4*)(wt1 + row * C_ + ck * 8);
        *(uint4*)(slA + row * 256 + ((ck * 16) ^ ((row & 7) << 4))) = v1;
        uint4 v2 = *(const uint4*)(wt2 + row * C_ + ck * 8);
        *(uint4*)(slB + row * 256 + ((ck * 16) ^ ((row & 7) << 4))) = v2;
    }
    __syncthreads();

    const int w = t >> 6, lane = t & 63;
    const int lr = lane & 15, lq = lane >> 4;
    const int wrn = w >> 1, wcc = w & 1;      // D[n][c]: 4 n-bands(64) x 2 c-bands(64)
    const int rn2 = w >> 2, cc4 = w & 3;      // G1c: 2 n-bands(64) x 4 c-bands(32)
    const int wct = w >> 2, wnt = w & 3;      // D[c][n]: 2 c-bands(64) x 4 n-bands(64)

    // ---- G1b: acc = xs·W1   (A xs ds, B W1 slA ds)
    f32x4 acc[4][4];
#pragma unroll
    for (int fm = 0; fm < 4; ++fm)
#pragma unroll
        for (int fn = 0; fn < 4; ++fn) acc[fm][fn] = f32x4{0.f, 0.f, 0.f, 0.f};
#pragma unroll
    for (int kk = 0; kk < 4; ++kk) {
        bf16x8 afr[4], bfr[4];
#pragma unroll
        for (int fm = 0; fm < 4; ++fm) {
            int n = wrn * 64 + fm * 16 + lr;
            afr[fm] = __builtin_bit_cast(bf16x8,
                *(const uint4*)(xs + n * 256 + ((kk * 64 + lq * 16) ^ ((n & 7) << 4))));
        }
#pragma unroll
        for (int fn = 0; fn < 4; ++fn) {
            int c = wcc * 64 + fn * 16 + lr;
            bfr[fn] = __builtin_bit_cast(bf16x8,
                *(const uint4*)(slA + c * 256 + ((kk * 64 + lq * 16) ^ ((c & 7) << 4))));
        }
#pragma unroll
        for (int fm = 0; fm < 4; ++fm)
#pragma unroll
            for (int fn = 0; fn < 4; ++fn)
                acc[fm][fn] = __builtin_amdgcn_mfma_f32_16x16x32_bf16(afr[fm], bfr[fn], acc[fm][fn], 0, 0, 0);
    }

    // ---- n-chunk loop (nk = 0,1): G1c -> Y2T chunk -> G2
    for (int nk = 0; nk < 2; ++nk) {
        f32x4 acc2[4][2];
#pragma unroll
        for (int fm = 0; fm < 4; ++fm)
#pragma unroll
            for (int fn = 0; fn < 2; ++fn) acc2[fm][fn] = f32x4{0.f, 0.f, 0.f, 0.f};
#pragma unroll
        for (int kk = 0; kk < 4; ++kk) {
            bf16x8 afr[4], bfr[2];
#pragma unroll
            for (int fm = 0; fm < 4; ++fm) {
                int n = nk * 128 + rn2 * 64 + fm * 16 + lr;
                afr[fm] = __builtin_bit_cast(bf16x8,
                    *(const uint4*)(xs + n * 256 + ((kk * 64 + lq * 16) ^ ((n & 7) << 4))));
            }
#pragma unroll
            for (int fn = 0; fn < 2; ++fn) {
                int c = cc4 * 32 + fn * 16 + lr;
                bfr[fn] = __builtin_bit_cast(bf16x8,
                    *(const uint4*)(slB + c * 256 + ((kk * 64 + lq * 16) ^ ((c & 7) << 4))));
            }
#pragma unroll
            for (int fm = 0; fm < 4; ++fm)
#pragma unroll
                for (int fn = 0; fn < 2; ++fn)
                    acc2[fm][fn] = __builtin_amdgcn_mfma_f32_16x16x32_bf16(afr[fm], bfr[fn], acc2[fm][fn], 0, 0, 0);
        }
        // prefetch adj A-frags for G2 kk=0,1 (independent of LDS; drains at barrier)
        bf16x8 padj[2][4];
#pragma unroll
        for (int kk2 = 0; kk2 < 2; ++kk2)
#pragma unroll
            for (int fm = 0; fm < 4; ++fm) {
                int n = wrn * 64 + fm * 16 + lr;
                padj[kk2][fm] = __builtin_bit_cast(bf16x8,
                    *(const uint4*)(adj + n * N_ + nk * 128 + kk2 * 32 + lq * 8));
            }
        __syncthreads();   // prior slA readers (G1b / previous G2) done
        // write Y2T chunk [128c][128n-local]
#pragma unroll
        for (int fm = 0; fm < 4; ++fm)
#pragma unroll
            for (int fn = 0; fn < 2; ++fn) {
                int c  = cc4 * 32 + fn * 16 + lr;
                int nl = rn2 * 64 + fm * 16 + lq * 4;
                f32x4 a = acc2[fm][fn];
                unsigned short tmp[4] __attribute__((aligned(8)));
#pragma unroll
                for (int r = 0; r < 4; ++r) tmp[r] = f2b(a[r]);
                *(uint2*)(slA + c * 256 + ((nl * 2) ^ ((c & 7) << 4))) = *(const uint2*)tmp;
            }
        __syncthreads();
        // G2: acc += adj[:, chunk] · Y2c   (A adj prefetched/global, B slA ds)
#pragma unroll
        for (int kk = 0; kk < 4; ++kk) {
            bf16x8 afr[4], bfr[4];
#pragma unroll
            for (int fm = 0; fm < 4; ++fm) {
                int n = wrn * 64 + fm * 16 + lr;
                afr[fm] = (kk < 2) ? padj[kk][fm] : __builtin_bit_cast(bf16x8,
                    *(const uint4*)(adj + n * N_ + nk * 128 + kk * 32 + lq * 8));
            }
#pragma unroll
            for (int fn = 0; fn < 4; ++fn) {
                int c = wcc * 64 + fn * 16 + lr;
                bfr[fn] = __builtin_bit_cast(bf16x8,
                    *(const uint4*)(slA + c * 256 + ((kk * 64 + lq * 16) ^ ((c & 7) << 4))));
            }
#pragma unroll
            for (int fm = 0; fm < 4; ++fm)
#pragma unroll
                for (int fn = 0; fn < 4; ++fn)
                    acc[fm][fn] = __builtin_amdgcn_mfma_f32_16x16x32_bf16(afr[fm], bfr[fn], acc[fm][fn], 0, 0, 0);
        }
    }

    // ---- cvt Z -> bf16 packed (frees acc)
    uint2 Zb[4][4];
#pragma unroll
    for (int fm = 0; fm < 4; ++fm)
#pragma unroll
        for (int fn = 0; fn < 4; ++fn) {
            f32x4 a = acc[fm][fn];
            unsigned short tmp[4] __attribute__((aligned(8)));
#pragma unroll
            for (int r = 0; r < 4; ++r) tmp[r] = f2b(a[r]);
            Zb[fm][fn] = *(const uint2*)tmp;
        }
    __syncthreads();   // G2-c1 slA reads + all W2 (slB) reads done

    // ---- stage W0 -> slB ; write ZT chunk0 -> slA (owners wrn<2)
#pragma unroll
    for (int j = 0; j < 4; ++j) {
        int ch = j * 512 + t; int row = ch >> 4, ck = ch & 15;
        uint4 v0 = *(const uint4*)(wt0 + row * C_ + ck * 8);
        *(uint4*)(slB + row * 256 + ((ck * 16) ^ ((row & 7) << 4))) = v0;
    }
    if (wrn < 2) {
#pragma unroll
        for (int fm = 0; fm < 4; ++fm)
#pragma unroll
            for (int fn = 0; fn < 4; ++fn) {
                int c  = wcc * 64 + fn * 16 + lr;
                int nl = wrn * 64 + fm * 16 + lq * 4;
                *(uint2*)(slA + c * 256 + ((nl * 2) ^ ((c & 7) << 4))) = Zb[fm][fn];
            }
    }
    __syncthreads();

    // ---- G1a: accO = bias + W0''T·xsT  (A slB ds, B xs ds), D[c][n]
    f32x4 accO[4][4];
#pragma unroll
    for (int fm = 0; fm < 4; ++fm) {
        float4 b4 = *(const float4*)(bias + wct * 64 + fm * 16 + lq * 4);
#pragma unroll
        for (int fn = 0; fn < 4; ++fn) accO[fm][fn] = f32x4{b4.x, b4.y, b4.z, b4.w};
    }
#pragma unroll
    for (int kk = 0; kk < 4; ++kk) {
        bf16x8 afr[4], bfr[4];
#pragma unroll
        for (int fm = 0; fm < 4; ++fm) {
            int d = wct * 64 + fm * 16 + lr;
            afr[fm] = __builtin_bit_cast(bf16x8,
                *(const uint4*)(slB + d * 256 + ((kk * 64 + lq * 16) ^ ((d & 7) << 4))));
        }
#pragma unroll
        for (int fn = 0; fn < 4; ++fn) {
            int n = wnt * 64 + fn * 16 + lr;
            bfr[fn] = __builtin_bit_cast(bf16x8,
                *(const uint4*)(xs + n * 256 + ((kk * 64 + lq * 16) ^ ((n & 7) << 4))));
        }
#pragma unroll
        for (int fm = 0; fm < 4; ++fm)
#pragma unroll
            for (int fn = 0; fn < 4; ++fn)
                accO[fm][fn] = __builtin_amdgcn_mfma_f32_16x16x32_bf16(afr[fm], bfr[fn], accO[fm][fn], 0, 0, 0);
    }

    // ---- ZT chunk loop + G3
    for (int nk = 0; nk < 2; ++nk) {
        // prefetch adj B-frags for G3 kk=0,1
        bf16x8 pb[2][4];
#pragma unroll
        for (int kk2 = 0; kk2 < 2; ++kk2)
#pragma unroll
            for (int fn = 0; fn < 4; ++fn) {
                int n = wnt * 64 + fn * 16 + lr;
                pb[kk2][fn] = __builtin_bit_cast(bf16x8,
                    *(const uint4*)(adj + n * N_ + nk * 128 + kk2 * 32 + lq * 8));
            }
        if (nk == 1) {
            __syncthreads();   // G3-c0 slA reads done
            if (wrn >= 2) {
#pragma unroll
                for (int fm = 0; fm < 4; ++fm)
#pragma unroll
                    for (int fn = 0; fn < 4; ++fn) {
                        int c  = wcc * 64 + fn * 16 + lr;
                        int nl = (wrn - 2) * 64 + fm * 16 + lq * 4;
                        *(uint2*)(slA + c * 256 + ((nl * 2) ^ ((c & 7) << 4))) = Zb[fm][fn];
                    }
            }
        }
        __syncthreads();
        // G3: accO += ZTc · adj[chunk,:]   (A slA ds, B adj prefetched/global)
#pragma unroll
        for (int kk = 0; kk < 4; ++kk) {
            bf16x8 afr[4], bfr[4];
#pragma unroll
            for (int fm = 0; fm < 4; ++fm) {
                int c = wct * 64 + fm * 16 + lr;
                afr[fm] = __builtin_bit_cast(bf16x8,
                    *(const uint4*)(slA + c * 256 + ((kk * 64 + lq * 16) ^ ((c & 7) << 4))));
            }
#pragma unroll
            for (int fn = 0; fn < 4; ++fn) {
                int n = wnt * 64 + fn * 16 + lr;
                bfr[fn] = (kk < 2) ? pb[kk][fn] : __builtin_bit_cast(bf16x8,
                    *(const uint4*)(adj + n * N_ + nk * 128 + kk * 32 + lq * 8));
            }
#pragma unroll
            for (int fm = 0; fm < 4; ++fm)
#pragma unroll
                for (int fn = 0; fn < 4; ++fn)
                    accO[fm][fn] = __builtin_amdgcn_mfma_f32_16x16x32_bf16(afr[fm], bfr[fn], accO[fm][fn], 0, 0, 0);
        }
    }

    // ---- store: D[c][n] frag = 4 consecutive c at one n -> float4
#pragma unroll
    for (int fm = 0; fm < 4; ++fm) {
        int c0 = wct * 64 + fm * 16 + lq * 4;
#pragma unroll
        for (int fn = 0; fn < 4; ++fn) {
            int n = wnt * 64 + fn * 16 + lr;
            *(float4*)(og + n * C_ + c0) = __builtin_bit_cast(float4, accO[fm][fn]);
        }
    }
}

// ---------------------------------------------------------------------------
// Kernel 2 (fallback): used only if ws too small for x'.
// ---------------------------------------------------------------------------
extern "C" __global__ __launch_bounds__(512, 2) void k_main_fb(
    const float* __restrict__ timep,
    const float* __restrict__ frep,
    const unsigned short* __restrict__ adj,
    const float* __restrict__ fused_ws,
    const float* __restrict__ scale_tp,
    const float* __restrict__ scale_fp,
    const unsigned short* __restrict__ wtp,
    const float* __restrict__ btp,
    const float* __restrict__ bfp,
    float* __restrict__ outp)
{
    extern __shared__ char smem[];
    char* cb = smem + 65536;
    float* fused_s = (float*)cb;
    const int t  = threadIdx.x;
    const int b  = blockIdx.x;
    const int br = blockIdx.y;
    const float* xg = (br ? frep : timep) + (size_t)b * (N_ * C_);
    const unsigned short* wt0 = wtp + br * (3 * C_ * C_);
    const unsigned short* wt1 = wt0 + C_ * C_;
    const unsigned short* wt2 = wt0 + 2 * C_ * C_;
    const float* bias = br ? bfp : btp;
    float* og = outp + (size_t)br * B_ * N_ * C_ + (size_t)b * (N_ * C_);
    const float scale = (br ? scale_fp : scale_tp)[0];

    fused_s[t] = fused_ws[(size_t)b * (L_ * C_) + t];
    __syncthreads();
    {
        const int n = t >> 1, h = t & 1;
        float xv[64];
        const float4* xr = (const float4*)(xg + n * C_ + h * 64);
#pragma unroll
        for (int i4 = 0; i4 < 16; ++i4) {
            float4 u = xr[i4];
            xv[i4 * 4 + 0] = u.x; xv[i4 * 4 + 1] = u.y;
            xv[i4 * 4 + 2] = u.z; xv[i4 * 4 + 3] = u.w;
        }
        float s0 = 0, s1 = 0, s2 = 0, s3 = 0;
#pragma unroll
        for (int k = 0; k < 64; ++k) {
            int c = h * 64 + k; float x = xv[k];
            s0 += x * fused_s[c];          s1 += x * fused_s[C_ + c];
            s2 += x * fused_s[2 * C_ + c]; s3 += x * fused_s[3 * C_ + c];
        }
        s0 += __shfl_xor(s0, 1); s1 += __shfl_xor(s1, 1);
        s2 += __shfl_xor(s2, 1); s3 += __shfl_xor(s3, 1);
        const float isc = 0.0883883476483184f;
        s0 *= isc; s1 *= isc; s2 *= isc; s3 *= isc;
        float m = fmaxf(fmaxf(s0, s1), fmaxf(s2, s3));
        float p0 = __expf(s0 - m), p1 = __expf(s1 - m), p2 = __expf(s2 - m), p3 = __expf(s3 - m);
        float inv = scale / (p0 + p1 + p2 + p3);
        p0 *= inv; p1 *= inv; p2 *= inv; p3 *= inv;
#pragma unroll
        for (int ci = 0; ci < 8; ++ci) {
            unsigned short ov[8] __attribute__((aligned(16)));
#pragma unroll
            for (int i = 0; i < 8; ++i) {
                int k = ci * 8 + i; int c = h * 64 + k;
                float v = xv[k] + p0 * fused_s[c] + p1 * fused_s[C_ + c]
                        + p2 * fused_s[2 * C_ + c] + p3 * fused_s[3 * C_ + c];
                ov[i] = f2b(v);
            }
            int chunk = h * 8 + ci;
            *(uint4*)(smem + n * 256 + ((chunk * 16) ^ ((n & 7) << 4))) = *(const uint4*)ov;
        }
    }
    __syncthreads();

    const int w = t >> 6, lane = t & 63;
    const int lr = lane & 15, lq = lane >> 4;
    const int wrn = w >> 1, wcc = w & 1;
    const int wct = w >> 2, wnt = w & 3;
    const int rn  = w >> 1;

    f32x4 acc[4][4];
#pragma unroll
    for (int fm = 0; fm < 4; ++fm)
#pragma unroll
        for (int fn = 0; fn < 4; ++fn) acc[fm][fn] = f32x4{0.f, 0.f, 0.f, 0.f};
#pragma unroll
    for (int kk = 0; kk < 4; ++kk) {
        bf16x8 afr[4], bfr[4];
#pragma unroll
        for (int fm = 0; fm < 4; ++fm) {
            int n = wrn * 64 + fm * 16 + lr;
            afr[fm] = __builtin_bit_cast(bf16x8,
                *(const uint4*)(smem + n * 256 + ((kk * 64 + lq * 16) ^ ((n & 7) << 4))));
        }
#pragma unroll
        for (int fn = 0; fn < 4; ++fn) {
            int d = wcc * 64 + fn * 16 + lr;
            bfr[fn] = __builtin_bit_cast(bf16x8, *(const uint4*)(wt1 + d * C_ + kk * 32 + lq * 8));
        }
#pragma unroll
        for (int fm = 0; fm < 4; ++fm)
#pragma unroll
            for (int fn = 0; fn < 4; ++fn)
                acc[fm][fn] = __builtin_amdgcn_mfma_f32_16x16x32_bf16(afr[fm], bfr[fn], acc[fm][fn], 0, 0, 0);
    }
    for (int ch = 0; ch < 4; ++ch) {
        f32x4 acc2[4];
#pragma unroll
        for (int fn = 0; fn < 4; ++fn) acc2[fn] = f32x4{0.f, 0.f, 0.f, 0.f};
#pragma unroll
        for (int kk = 0; kk < 4; ++kk) {
            int n = ch * 64 + rn * 16 + lr;
            bf16x8 a = __builtin_bit_cast(bf16x8,
                *(const uint4*)(smem + n * 256 + ((kk * 64 + lq * 16) ^ ((n & 7) << 4))));
#pragma unroll
            for (int fn = 0; fn < 4; ++fn) {
                int d = wcc * 64 + fn * 16 + lr;
                bf16x8 bfr = __builtin_bit_cast(bf16x8, *(const uint4*)(wt2 + d * C_ + kk * 32 + lq * 8));
                acc2[fn] = __builtin_amdgcn_mfma_f32_16x16x32_bf16(a, bfr, acc2[fn], 0, 0, 0);
            }
        }
#pragma unroll
        for (int fn = 0; fn < 4; ++fn) {
            int c   = wcc * 64 + fn * 16 + lr;
            int n0l = rn * 16 + lq * 4;
            f32x4 a = acc2[fn];
            unsigned short tmp[4] __attribute__((aligned(8)));
#pragma unroll
            for (int r = 0; r < 4; ++r) tmp[r] = f2b(a[r]);
            *(uint2*)(cb + c * 128 + ((n0l * 2) ^ ((c & 7) << 4))) = *(const uint2*)tmp;
        }
        __syncthreads();
#pragma unroll
        for (int kk = 0; kk < 2; ++kk) {
            bf16x8 afr[4], bfr[4];
#pragma unroll
            for (int fm = 0; fm < 4; ++fm) {
                int n = wrn * 64 + fm * 16 + lr;
                afr[fm] = __builtin_bit_cast(bf16x8,
                    *(const uint4*)(adj + n * N_ + ch * 64 + kk * 32 + lq * 8));
            }
#pragma unroll
            for (int fn = 0; fn < 4; ++fn) {
                int c = wcc * 64 + fn * 16 + lr;
                bfr[fn] = __builtin_bit_cast(bf16x8,
                    *(const uint4*)(cb + c * 128 + ((kk * 64 + lq * 16) ^ ((c & 7) << 4))));
            }
#pragma unroll
            for (int fm = 0; fm < 4; ++fm)
#pragma unroll
                for (int fn = 0; fn < 4; ++fn)
                    acc[fm][fn] = __builtin_amdgcn_mfma_f32_16x16x32_bf16(afr[fm], bfr[fn], acc[fm][fn], 0, 0, 0);
        }
        __syncthreads();
    }
    uint2 Zb[4][4];
#pragma unroll
    for (int fm = 0; fm < 4; ++fm)
#pragma unroll
        for (int fn = 0; fn < 4; ++fn) {
            f32x4 a = acc[fm][fn];
            unsigned short tmp[4] __attribute__((aligned(8)));
#pragma unroll
            for (int r = 0; r < 4; ++r) tmp[r] = f2b(a[r]);
            Zb[fm][fn] = *(const uint2*)tmp;
        }
    f32x4 accO[4][4];
#pragma unroll
    for (int fm = 0; fm < 4; ++fm) {
        float4 b4 = *(const float4*)(bias + wct * 64 + fm * 16 + lq * 4);
#pragma unroll
        for (int fn = 0; fn < 4; ++fn) accO[fm][fn] = f32x4{b4.x, b4.y, b4.z, b4.w};
    }
#pragma unroll
    for (int kk = 0; kk < 4; ++kk) {
        bf16x8 afr[4], bfr[4];
#pragma unroll
        for (int fm = 0; fm < 4; ++fm) {
            int d = wct * 64 + fm * 16 + lr;
            afr[fm] = __builtin_bit_cast(bf16x8, *(const uint4*)(wt0 + d * C_ + kk * 32 + lq * 8));
        }
#pragma unroll
        for (int fn = 0; fn < 4; ++fn) {
            int n = wnt * 64 + fn * 16 + lr;
            bfr[fn] = __builtin_bit_cast(bf16x8,
                *(const uint4*)(smem + n * 256 + ((kk * 64 + lq * 16) ^ ((n & 7) << 4))));
        }
#pragma unroll
        for (int fm = 0; fm < 4; ++fm)
#pragma unroll
            for (int fn = 0; fn < 4; ++fn)
                accO[fm][fn] = __builtin_amdgcn_mfma_f32_16x16x32_bf16(afr[fm], bfr[fn], accO[fm][fn], 0, 0, 0);
    }
    for (int ch = 0; ch < 4; ++ch) {
        if (wrn == ch) {
#pragma unroll
            for (int fm = 0; fm < 4; ++fm)
#pragma unroll
                for (int fn = 0; fn < 4; ++fn) {
                    int c   = wcc * 64 + fn * 16 + lr;
                    int n0l = fm * 16 + lq * 4;
                    *(uint2*)(cb + c * 128 + ((n0l * 2) ^ ((c & 7) << 4))) = Zb[fm][fn];
                }
        }
        __syncthreads();
#pragma unroll
        for (int kk = 0; kk < 2; ++kk) {
            bf16x8 afr[4], bfr[4];
#pragma unroll
            for (int fm = 0; fm < 4; ++fm) {
                int c = wct * 64 + fm * 16 + lr;
                afr[fm] = __builtin_bit_cast(bf16x8,
                    *(const uint4*)(cb + c * 128 + ((kk * 64 + lq * 16) ^ ((c & 7) << 4))));
            }
#pragma unroll
            for (int fn = 0; fn < 4; ++fn) {
                int n = wnt * 64 + fn * 16 + lr;
                bfr[fn] = __builtin_bit_cast(bf16x8,
                    *(const uint4*)(adj + n * N_ + ch * 64 + kk * 32 + lq * 8));
            }
#pragma unroll
            for (int fm = 0; fm < 4; ++fm)
#pragma unroll
                for (int fn = 0; fn < 4; ++fn)
                    accO[fm][fn] = __builtin_amdgcn_mfma_f32_16x16x32_bf16(afr[fm], bfr[fn], accO[fm][fn], 0, 0, 0);
        }
        __syncthreads();
    }
#pragma unroll
    for (int fm = 0; fm < 4; ++fm) {
        int c0 = wct * 64 + fm * 16 + lq * 4;
#pragma unroll
        for (int fn = 0; fn < 4; ++fn) {
            int n = wnt * 64 + fn * 16 + lr;
            *(float4*)(og + n * C_ + c0) = __builtin_bit_cast(float4, accO[fm][fn]);
        }
    }
}

// ---------------------------------------------------------------------------
extern "C" void kernel_launch(void* const* d_in, const int* in_sizes, int n_in,
                              void* d_out, int out_size, void* d_ws, size_t ws_size,
                              hipStream_t stream)
{
    const float* timep = (const float*)d_in[0];
    const float* frep  = (const float*)d_in[1];
    const float* adjf  = (const float*)d_in[2];
    const float* lat   = (const float*)d_in[3];
    const float* sct   = (const float*)d_in[4];
    const float* scf   = (const float*)d_in[5];
    const float* Wt    = (const float*)d_in[6];
    const float* bt    = (const float*)d_in[7];
    const float* Wf    = (const float*)d_in[8];
    const float* bf    = (const float*)d_in[9];
    float* outp = (float*)d_out;

    float* fused_ws        = (float*)d_ws;                                        // 2 MB
    unsigned short* wtp    = (unsigned short*)((char*)d_ws + 2097152);            // 192 KB
    unsigned short* adj_bs = (unsigned short*)((char*)d_ws + 2097152 + 196608);   // 128 KB
    unsigned short* xpws   = (unsigned short*)((char*)d_ws + 4194304);            // 128 MB

    const size_t need = 4194304ull + 134217728ull;
    const int fast = (ws_size >= need) ? 1 : 0;

    hipFuncSetAttribute((const void*)k_latent,  hipFuncAttributeMaxDynamicSharedMemorySize, 145408);
    hipFuncSetAttribute((const void*)k_cheb,    hipFuncAttributeMaxDynamicSharedMemorySize, 131072);
    hipFuncSetAttribute((const void*)k_main_fb, hipFuncAttributeMaxDynamicSharedMemorySize, 81920);

    k_prep<<<640, 256, 0, stream>>>(Wt, Wf, adjf, wtp, adj_bs);
    k_latent<<<1024, 512, 145408, stream>>>(timep, frep, lat, sct, scf,
                                            fused_ws, xpws, fast);
    if (fast) {
        k_cheb<<<dim3(1024, 2), 512, 131072, stream>>>(adj_bs, wtp, bt, bf, xpws, outp);
    } else {
        k_main_fb<<<dim3(1024, 2), 512, 81920, stream>>>(timep, frep, adj_bs, fused_ws,
                                                         sct, scf, wtp, bt, bf, outp);
    }
}